// Round 4
// baseline (287.982 us; speedup 1.0000x reference)
//
#include <hip/hip_runtime.h>

#define EPSF 1e-6f

typedef _Float16 f16x8 __attribute__((ext_vector_type(8)));
typedef _Float16 f16x4 __attribute__((ext_vector_type(4)));
typedef float    f32x4 __attribute__((ext_vector_type(4)));

#define GLL16(gp, lp) __builtin_amdgcn_global_load_lds( \
    (const __attribute__((address_space(1))) void*)(gp), \
    (__attribute__((address_space(3))) void*)(lp), 16, 0, 0)

// ---------------- elementwise f32 -> f16 convert (vectorized) ----------------
__global__ __launch_bounds__(256) void cvt_f16(const float* __restrict__ in,
                                               _Float16* __restrict__ out, int n8) {
    int idx = blockIdx.x * 256 + threadIdx.x;
    int stride = gridDim.x * 256;
    for (; idx < n8; idx += stride) {
        const float4* p = (const float4*)in + (size_t)idx * 2;
        float4 a = p[0], b = p[1];
        f16x8 o;
        o[0] = (_Float16)a.x; o[1] = (_Float16)a.y; o[2] = (_Float16)a.z; o[3] = (_Float16)a.w;
        o[4] = (_Float16)b.x; o[5] = (_Float16)b.y; o[6] = (_Float16)b.z; o[7] = (_Float16)b.w;
        *(f16x8*)(out + (size_t)idx * 8) = o;
    }
}

// ---------------- build block-diagonal omega, transposed, f16 ----------------
__global__ __launch_bounds__(256) void build_obdT(const float* __restrict__ omega,
                                                  _Float16* __restrict__ obdT) {
    int idx = blockIdx.x * 256 + threadIdx.x;   // over 1M
    int c = idx >> 10, k = idx & 1023;
    float v = ((c >> 6) == (k >> 6)) ? omega[(k & 63) * 64 + (c & 63)] : 0.f;
    obdT[idx] = (_Float16)v;
}

// ---------------- transpose 1024x1024 f32 -> f16 ----------------
__global__ __launch_bounds__(256) void transpose_cvt(const float* __restrict__ in,
                                                     _Float16* __restrict__ out) {
    __shared__ float tile[64][65];
    const int t = threadIdx.x;
    const int k0 = blockIdx.x * 64, n0 = blockIdx.y * 64;
#pragma unroll
    for (int j = 0; j < 16; j++) {
        int idx = j * 256 + t; int r = idx >> 6, c = idx & 63;
        tile[r][c] = in[(size_t)(k0 + r) * 1024 + n0 + c];
    }
    __syncthreads();
#pragma unroll
    for (int j = 0; j < 16; j++) {
        int idx = j * 256 + t; int rn = idx >> 6, ck = idx & 63;
        out[(size_t)(n0 + rn) * 1024 + k0 + ck] = (_Float16)tile[ck][rn];
    }
}

// ---------------- fused bias prep: bQf = bQ@omega, bkv = [bK@omega ; bV] ----------------
__global__ __launch_bounds__(256) void prep_bias(const float* __restrict__ bQ,
                                                 const float* __restrict__ bK,
                                                 const float* __restrict__ bV,
                                                 const float* __restrict__ omega,
                                                 float* __restrict__ bQf,
                                                 float* __restrict__ bkv) {
    int c = blockIdx.x * 256 + threadIdx.x;  // 0..1023
    int h = c >> 6, e = c & 63;
    float sq = 0.f, sk = 0.f;
    for (int d = 0; d < 64; d++) {
        float o = omega[d * 64 + e];
        sq += bQ[h * 64 + d] * o;
        sk += bK[h * 64 + d] * o;
    }
    bQf[c] = sq;
    bkv[c] = sk;
    bkv[1024 + c] = bV[c];
}

// ---------------- fold GEMM (m97 128^2 structure): [WQ;WK](2048x1024) @ obdT^T ----------------
__global__ __launch_bounds__(256) void gemm_fold(const _Float16* __restrict__ A,
                                                 const _Float16* __restrict__ Bt,
                                                 _Float16* __restrict__ out0,
                                                 _Float16* __restrict__ out1) {
    const int K = 1024;
    __shared__ __align__(16) _Float16 Asm[128 * 32];
    __shared__ __align__(16) _Float16 Bsm[128 * 32];
    const int t = threadIdx.x, lane = t & 63, w = t >> 6;
    const int bm = blockIdx.y * 128, bn = blockIdx.x * 128;
    const int wm = (w >> 1) * 64, wn = (w & 1) * 64;
    const int r15 = lane & 15, slog = lane >> 4;

    int aoff[4], boff[4];
#pragma unroll
    for (int m = 0; m < 4; m++) {
        int ra = wm + m * 16 + r15;
        aoff[m] = ra * 32 + (slog ^ ((ra >> 1) & 3)) * 8;
        int rb = wn + m * 16 + r15;
        boff[m] = rb * 32 + (slog ^ ((rb >> 1) & 3)) * 8;
    }
    f32x4 acc[4][4];
#pragma unroll
    for (int m = 0; m < 4; m++)
#pragma unroll
        for (int n = 0; n < 4; n++) acc[m][n] = (f32x4){0.f, 0.f, 0.f, 0.f};

    for (int kt = 0; kt < K; kt += 32) {
        __syncthreads();
#pragma unroll
        for (int i = 0; i < 2; i++) {
            int seg = i * 256 + w * 64 + lane;
            int r = seg >> 2, sp = seg & 3;
            int sg = sp ^ ((r >> 1) & 3);
            GLL16(A  + (size_t)(bm + r) * K + kt + sg * 8, Asm + (size_t)(i * 256 + w * 64) * 8);
            GLL16(Bt + (size_t)(bn + r) * K + kt + sg * 8, Bsm + (size_t)(i * 256 + w * 64) * 8);
        }
        __syncthreads();
        f16x8 av[4], bv[4];
#pragma unroll
        for (int m = 0; m < 4; m++) av[m] = *(const f16x8*)(Asm + aoff[m]);
#pragma unroll
        for (int n = 0; n < 4; n++) bv[n] = *(const f16x8*)(Bsm + boff[n]);
#pragma unroll
        for (int m = 0; m < 4; m++)
#pragma unroll
            for (int n = 0; n < 4; n++)
                acc[m][n] = __builtin_amdgcn_mfma_f32_16x16x32_f16(av[m], bv[n], acc[m][n], 0, 0, 0);
    }

#pragma unroll
    for (int m = 0; m < 4; m++) {
        int row0 = bm + wm + m * 16 + slog * 4;
        _Float16* C = (row0 < 1024) ? out0 : out1;
        int l = row0 & 1023;
#pragma unroll
        for (int n = 0; n < 4; n++) {
            int colg = bn + wn + n * 16 + r15;
            f16x4 p;
#pragma unroll
            for (int j = 0; j < 4; j++) p[j] = (_Float16)acc[m][n][j];
            *(f16x4*)(C + (size_t)colg * 1024 + l) = p;
        }
    }
}

// ---------------- big GEMM: 256x256 tile, BK=32 slab, 4-slab ring, 2-phase/slab ----------------
// LDS ring: 4 slabs x 32KB { A 256x32 f16 @ +0, B 256x32 f16 @ +16384 }.
// Slab row = 64 B; phys 16B slot = (logical_slot + (row>>1)) & 3 (rotate swizzle).
// Schedule (8-phase template style): per slab two phases, each
//   {ds_read subtile ; [stage / counted vmcnt] ; barrier ; lgkmcnt(0) ; setprio ; 16 MFMA ; barrier}
// vmcnt never drains to 0 mid-loop; slab-landed sync lives in previous slab's phase B.
// EPI: 1 = relu+eps -> f16 [M][N];  2 = linear -> f32 [M][N];
//      3 = split transposed (col<1024: relu+eps -> out0 [head][d][l]; else linear -> out1)
template<int EPI>
__global__ __launch_bounds__(512, 2) void gemm256(const _Float16* __restrict__ A,
                                                  const _Float16* __restrict__ Bt,
                                                  const float* __restrict__ bias,
                                                  void* __restrict__ out0,
                                                  void* __restrict__ out1,
                                                  int M, int N, int K, int nbn) {
    __shared__ __align__(16) char lds[131072];
    const int t = threadIdx.x, lane = t & 63, w = t >> 6;
    const int nwg = gridDim.x;
    const int f = (blockIdx.x & 7) * (nwg >> 3) + (blockIdx.x >> 3);   // bijective XCD swizzle
    const int bm = (f / nbn) * 256, bn = (f % nbn) * 256;
    const int wm = (w & 1) * 128, wn = (w >> 1) * 64;
    const int r15 = lane & 15, hi = lane >> 4;
    const int srow = lane >> 2, sp = lane & 3;     // staging: 16 rows/gll, 4 slots/row

    int aoff[8], boff[4];
#pragma unroll
    for (int m = 0; m < 8; m++) {
        int r = wm + m * 16 + r15;
        aoff[m] = r * 64 + (((hi + (r >> 1)) & 3) << 4);
    }
#pragma unroll
    for (int n = 0; n < 4; n++) {
        int r = wn + n * 16 + r15;
        boff[n] = r * 64 + (((hi + (r >> 1)) & 3) << 4);
    }

    f32x4 acc[8][4];
#pragma unroll
    for (int m = 0; m < 8; m++)
#pragma unroll
        for (int n = 0; n < 4; n++) acc[m][n] = (f32x4){0.f, 0.f, 0.f, 0.f};

    auto stage = [&](int s) {
        char* base = lds + (s & 3) * 32768;
        int kt = s * 32;
#pragma unroll
        for (int p = 0; p < 2; p++) {
            int row = w * 32 + p * 16 + srow;
            int sg = (sp - ((row >> 1) & 3)) & 3;   // pre-swizzled global slot
            GLL16(A  + (size_t)(bm + row) * K + kt + sg * 8, base + w * 2048 + p * 1024);
            GLL16(Bt + (size_t)(bn + row) * K + kt + sg * 8, base + 16384 + w * 2048 + p * 1024);
        }
    };

    const int NS = K >> 5;
    stage(0); stage(1); stage(2);
    asm volatile("s_waitcnt vmcnt(8)" ::: "memory");   // slab 0 landed
    asm volatile("s_barrier" ::: "memory");
    for (int s = 0; s < NS; ++s) {
        const char* La = lds + (s & 3) * 32768;
        const char* Lb = La + 16384;
        // -------- phase A: stage s+3, read bv + av[0..3], MFMA m0..3 --------
        if (s + 3 < NS) stage(s + 3);                // buf (s-1)&3: reads finished last slab
        f16x8 bv[4], avL[4];
#pragma unroll
        for (int n = 0; n < 4; n++) bv[n] = *(const f16x8*)(Lb + boff[n]);
#pragma unroll
        for (int m = 0; m < 4; m++) avL[m] = *(const f16x8*)(La + aoff[m]);
        asm volatile("s_barrier" ::: "memory");
        asm volatile("s_waitcnt lgkmcnt(0)" ::: "memory");
        __builtin_amdgcn_s_setprio(1);
#pragma unroll
        for (int m = 0; m < 4; m++)
#pragma unroll
            for (int n = 0; n < 4; n++)
                acc[m][n] = __builtin_amdgcn_mfma_f32_16x16x32_f16(avL[m], bv[n], acc[m][n], 0, 0, 0);
        __builtin_amdgcn_s_setprio(0);
        asm volatile("s_barrier" ::: "memory");
        // -------- phase B: read av[4..7], counted vmcnt (slab s+1 landed), MFMA m4..7 --------
        f16x8 avH[4];
#pragma unroll
        for (int m = 0; m < 4; m++) avH[m] = *(const f16x8*)(La + aoff[m + 4]);
        if (s + 3 < NS)      asm volatile("s_waitcnt vmcnt(8)" ::: "memory");
        else if (s + 2 < NS) asm volatile("s_waitcnt vmcnt(4)" ::: "memory");
        else                 asm volatile("s_waitcnt vmcnt(0)" ::: "memory");
        asm volatile("s_barrier" ::: "memory");
        asm volatile("s_waitcnt lgkmcnt(0)" ::: "memory");
        __builtin_amdgcn_s_setprio(1);
#pragma unroll
        for (int m = 0; m < 4; m++)
#pragma unroll
            for (int n = 0; n < 4; n++)
                acc[m + 4][n] = __builtin_amdgcn_mfma_f32_16x16x32_f16(avH[m], bv[n], acc[m + 4][n], 0, 0, 0);
        __builtin_amdgcn_s_setprio(0);
        asm volatile("s_barrier" ::: "memory");
    }

    if (EPI == 3) {
        // transposed epilogue via per-wave LDS tile [d=64][l=128] f16 (16 KB), swizzled
        char* LW = lds + w * 16384;
        const int colg0 = bn + wn;
        const bool isK = colg0 < 1024;
        _Float16* Cb = isK ? (_Float16*)out0 : (_Float16*)out1;
        const int hd = (isK ? colg0 : colg0 - 1024) >> 6;
        const int nb = bm >> 12;
        const int l0 = (bm & 4095) + wm;
#pragma unroll
        for (int m = 0; m < 8; m++)
#pragma unroll
            for (int n = 0; n < 4; n++) {
                int d = n * 16 + r15;
                float bs = bias[colg0 + d];
                f16x4 pk;
#pragma unroll
                for (int j = 0; j < 4; j++) {
                    float xv = acc[m][n][j] + bs;
                    if (isK) xv = fmaxf(xv, 0.f) + EPSF;
                    pk[j] = (_Float16)xv;
                }
                *(f16x4*)(LW + d * 256 + ((m * 32 + hi * 8) ^ ((d & 15) << 4))) = pk;
            }
        _Float16* basep = Cb + (size_t)(nb * 16 + hd) * 64 * 4096 + l0;
#pragma unroll
        for (int pass = 0; pass < 16; pass++) {
            int d = pass * 4 + hi;
            f16x8 v = *(const f16x8*)(LW + d * 256 + ((r15 * 16) ^ ((d & 15) << 4)));
            *(f16x8*)(basep + (size_t)d * 4096 + r15 * 8) = v;
        }
    } else {
#pragma unroll
        for (int m = 0; m < 8; m++) {
            int row0 = bm + wm + m * 16 + hi * 4;
#pragma unroll
            for (int n = 0; n < 4; n++) {
                int colg = bn + wn + n * 16 + r15;
                float bs = bias ? bias[colg] : 0.f;
#pragma unroll
                for (int j = 0; j < 4; j++) {
                    float xv = acc[m][n][j] + bs;
                    if (EPI == 1) {
                        xv = fmaxf(xv, 0.f) + EPSF;
                        ((_Float16*)out0)[(size_t)(row0 + j) * N + colg] = (_Float16)xv;
                    } else {
                        ((float*)out0)[(size_t)(row0 + j) * N + colg] = xv;
                    }
                }
            }
        }
    }
}

// ---------------- ksum[head][d] = sum_l KphiT[head][d][l] ----------------
__global__ __launch_bounds__(256) void ksum_kernel(const _Float16* __restrict__ KphiT,
                                                   float* __restrict__ ksum) {
    const int t = threadIdx.x, lane = t & 63, w = t >> 6;
    const int gid = blockIdx.x;          // 0..1023
    const int head = gid >> 4;
    const int d = (gid & 15) * 4 + w;
    const _Float16* src = KphiT + ((size_t)head * 64 + d) * 4096;
    float s = 0.f;
#pragma unroll
    for (int i = 0; i < 8; i++) {
        f16x8 v = *(const f16x8*)(src + (size_t)(i * 64 + lane) * 8);
#pragma unroll
        for (int j = 0; j < 8; j++) s += (float)v[j];
    }
#pragma unroll
    for (int o = 32; o; o >>= 1) s += __shfl_xor(s, o, 64);
    if (lane == 0) ksum[(size_t)head * 64 + d] = s;
}

// ---------------- kv partials ----------------
__global__ __launch_bounds__(256) void kvt_kernel(const _Float16* __restrict__ Vt,
                                                  const _Float16* __restrict__ KphiT,
                                                  float* __restrict__ kvpart) {
    const int t = threadIdx.x, lane = t & 63, w = t >> 6;
    const int head = blockIdx.y;
    const int l0 = blockIdx.x * 1024;
    __shared__ __align__(16) _Float16 As[64 * 128];
    __shared__ __align__(16) _Float16 Bs[64 * 128];
    const int r15 = lane & 15, slog = lane >> 4;
    f32x4 acc[4][4];
#pragma unroll
    for (int m = 0; m < 4; m++)
#pragma unroll
        for (int n = 0; n < 4; n++) acc[m][n] = (f32x4){0.f, 0.f, 0.f, 0.f};

    for (int it = 0; it < 8; it++) {
        __syncthreads();
        int lbase = l0 + it * 128;
#pragma unroll
        for (int i = 0; i < 4; i++) {
            int seg = i * 256 + w * 64 + lane;
            int r = seg >> 4, sp2 = seg & 15;
            int sg = sp2 ^ (r & 15);
            GLL16(Vt    + ((size_t)head * 64 + r) * 4096 + lbase + sg * 8, As + (size_t)(i * 256 + w * 64) * 8);
            GLL16(KphiT + ((size_t)head * 64 + r) * 4096 + lbase + sg * 8, Bs + (size_t)(i * 256 + w * 64) * 8);
        }
        __syncthreads();
        f16x8 av[4], bv[4];
#pragma unroll
        for (int m = 0; m < 4; m++) {
            int r = m * 16 + r15;
            int s2 = w * 4 + slog;
            int ph = s2 ^ (r & 15);
            av[m] = *(const f16x8*)(As + r * 128 + ph * 8);
            bv[m] = *(const f16x8*)(Bs + r * 128 + ph * 8);
        }
#pragma unroll
        for (int m = 0; m < 4; m++)
#pragma unroll
            for (int n = 0; n < 4; n++)
                acc[m][n] = __builtin_amdgcn_mfma_f32_16x16x32_f16(av[m], bv[n], acc[m][n], 0, 0, 0);
    }
    float* red = (float*)As;
    for (int ww = 0; ww < 4; ww++) {
        __syncthreads();
        if (w == ww) {
#pragma unroll
            for (int m = 0; m < 4; m++)
#pragma unroll
                for (int n = 0; n < 4; n++)
#pragma unroll
                    for (int j = 0; j < 4; j++) {
                        int row = m * 16 + slog * 4 + j, col = n * 16 + r15;
                        if (ww == 0) red[row * 64 + col] = acc[m][n][j];
                        else         red[row * 64 + col] += acc[m][n][j];
                    }
        }
    }
    __syncthreads();
    float* outp = kvpart + ((size_t)head * 4 + blockIdx.x) * 4096;
#pragma unroll
    for (int i = 0; i < 16; i++) { int idx = i * 256 + t; outp[idx] = red[idx]; }
}

// ---------------- numerator GEMM + denominator + divide -> U (f16) ----------------
// reads kvpart (4 chunks, summed inline; kvreduce fused away)
__global__ __launch_bounds__(256) void numdiv_kernel(const _Float16* __restrict__ Qphi,
                                                     const float* __restrict__ kvpart,
                                                     const float* __restrict__ ksum,
                                                     _Float16* __restrict__ U) {
    const int t = threadIdx.x, lane = t & 63, w = t >> 6;
    const int h = blockIdx.y;
    const int m0 = blockIdx.x * 256;
    const int nb = m0 >> 12;
    const int head = nb * 16 + h;
    __shared__ __align__(16) _Float16 Qs[256 * 64];
    __shared__ __align__(16) _Float16 Bs[64 * 64];
    __shared__ float ksl[64];

#pragma unroll
    for (int i = 0; i < 8; i++) {
        int seg = i * 256 + w * 64 + lane;
        int r = seg >> 3, sp = seg & 7;
        int sg = sp ^ (r & 7);
        GLL16(Qphi + (size_t)(m0 + r) * 1024 + h * 64 + sg * 8, Qs + (size_t)(i * 256 + w * 64) * 8);
    }
#pragma unroll
    for (int i = 0; i < 2; i++) {
        int sidx = i * 256 + t;
        int r = sidx >> 3, p = sidx & 7;
        int sg = p ^ (r & 7);
        const float* s0 = kvpart + (size_t)head * 4 * 4096 + r * 64 + sg * 8;
        float4 v0 = {0.f, 0.f, 0.f, 0.f}, v1 = {0.f, 0.f, 0.f, 0.f};
#pragma unroll
        for (int c = 0; c < 4; c++) {
            float4 a = *(const float4*)(s0 + c * 4096);
            float4 b = *(const float4*)(s0 + c * 4096 + 4);
            v0.x += a.x; v0.y += a.y; v0.z += a.z; v0.w += a.w;
            v1.x += b.x; v1.y += b.y; v1.z += b.z; v1.w += b.w;
        }
        f16x8 o;
        o[0] = (_Float16)v0.x; o[1] = (_Float16)v0.y; o[2] = (_Float16)v0.z; o[3] = (_Float16)v0.w;
        o[4] = (_Float16)v1.x; o[5] = (_Float16)v1.y; o[6] = (_Float16)v1.z; o[7] = (_Float16)v1.w;
        *(f16x8*)(Bs + sidx * 8) = o;
    }
    if (t < 64) ksl[t] = ksum[(size_t)head * 64 + t];
    __syncthreads();

    const int r15 = lane & 15, slog = lane >> 4;
    f32x4 acc[4][4];
#pragma unroll
    for (int m = 0; m < 4; m++)
#pragma unroll
        for (int n = 0; n < 4; n++) acc[m][n] = (f32x4){0.f, 0.f, 0.f, 0.f};
    float dp[4] = {0.f, 0.f, 0.f, 0.f};

#pragma unroll
    for (int kk = 0; kk < 2; kk++) {
        float ks[8];
#pragma unroll
        for (int j = 0; j < 8; j++) ks[j] = ksl[kk * 32 + slog * 8 + j];
        f16x8 av[4], bv[4];
#pragma unroll
        for (int m = 0; m < 4; m++) {
            int r = w * 64 + m * 16 + r15;
            int ph = (kk * 4 + slog) ^ (r & 7);
            av[m] = *(const f16x8*)(Qs + r * 64 + ph * 8);
        }
#pragma unroll
        for (int n = 0; n < 4; n++) {
            int r = n * 16 + r15;
            int ph = (kk * 4 + slog) ^ (r & 7);
            bv[n] = *(const f16x8*)(Bs + r * 64 + ph * 8);
        }
#pragma unroll
        for (int m = 0; m < 4; m++)
#pragma unroll
            for (int j = 0; j < 8; j++) dp[m] += (float)av[m][j] * ks[j];
#pragma unroll
        for (int m = 0; m < 4; m++)
#pragma unroll
            for (int n = 0; n < 4; n++)
                acc[m][n] = __builtin_amdgcn_mfma_f32_16x16x32_f16(av[m], bv[n], acc[m][n], 0, 0, 0);
    }
#pragma unroll
    for (int m = 0; m < 4; m++) {
        dp[m] += __shfl_xor(dp[m], 16, 64);
        dp[m] += __shfl_xor(dp[m], 32, 64);
    }
#pragma unroll
    for (int m = 0; m < 4; m++) {
#pragma unroll
        for (int j = 0; j < 4; j++) {
            float den = __shfl(dp[m], slog * 4 + j, 64);
            float inv = __builtin_amdgcn_rcpf(den);
            int row = m0 + w * 64 + m * 16 + slog * 4 + j;
#pragma unroll
            for (int n = 0; n < 4; n++)
                U[(size_t)row * 1024 + h * 64 + n * 16 + r15] = (_Float16)(acc[m][n][j] * inv);
        }
    }
}

// ------------------------------------------------------------------------------------
extern "C" void kernel_launch(void* const* d_in, const int* in_sizes, int n_in,
                              void* d_out, int out_size, void* d_ws, size_t ws_size,
                              hipStream_t stream) {
    (void)in_sizes; (void)n_in; (void)out_size; (void)ws_size;
    const float* x     = (const float*)d_in[0];
    const float* y     = (const float*)d_in[1];
    const float* WQ    = (const float*)d_in[2];
    const float* bQ    = (const float*)d_in[3];
    const float* WK    = (const float*)d_in[4];
    const float* bK    = (const float*)d_in[5];
    const float* WV    = (const float*)d_in[6];
    const float* bV    = (const float*)d_in[7];
    const float* WO    = (const float*)d_in[8];
    const float* bO    = (const float*)d_in[9];
    const float* omega = (const float*)d_in[10];

    char* ws = (char*)d_ws;
    size_t off = 0;
    auto alloc = [&](size_t bytes) { void* p = ws + off; off += (bytes + 255) & ~(size_t)255; return p; };
    const size_t BIG = (size_t)16384 * 1024 * 2;    // 32 MiB f16
    _Float16* xb    = (_Float16*)alloc(BIG);        // reused for U later
    _Float16* yb    = (_Float16*)alloc(BIG);
    _Float16* WQKb  = (_Float16*)alloc((size_t)2048 * 1024 * 2);  // stacked WQ;WK f16
    _Float16* obdT  = (_Float16*)alloc(1024 * 1024 * 2);
    _Float16* Wqt   = (_Float16*)alloc(1024 * 1024 * 2);
    _Float16* Wkvt  = (_Float16*)alloc((size_t)2048 * 1024 * 2);  // rows 0-1023: K-fold, 1024-2047: V^T
    _Float16* Wot   = (_Float16*)alloc(1024 * 1024 * 2);
    float*    bQf   = (float*)alloc(1024 * 4);
    float*    bkv   = (float*)alloc(2048 * 4);
    _Float16* Qphi  = (_Float16*)alloc(BIG);
    _Float16* KphiT = (_Float16*)alloc(BIG);
    _Float16* Vt    = (_Float16*)alloc(BIG);
    float*    kvpart= (float*)alloc((size_t)256 * 4096 * 4);
    float*    ksum  = (float*)alloc((size_t)64 * 64 * 4);
    _Float16* U     = xb;  // alias: xb dead after Qphi GEMM

    // 1. precision converts
    cvt_f16<<<2048, 256, 0, stream>>>(x, xb, 16384 * 1024 / 8);
    cvt_f16<<<2048, 256, 0, stream>>>(y, yb, 16384 * 1024 / 8);
    cvt_f16<<<512, 256, 0, stream>>>(WQ, WQKb, 1024 * 1024 / 8);
    cvt_f16<<<512, 256, 0, stream>>>(WK, WQKb + (size_t)1024 * 1024, 1024 * 1024 / 8);
    // 2. omega block-diag (transposed) + weight transposes + bias prep
    build_obdT<<<4096, 256, 0, stream>>>(omega, obdT);
    transpose_cvt<<<dim3(16, 16), 256, 0, stream>>>(WV, Wkvt + (size_t)1024 * 1024);
    transpose_cvt<<<dim3(16, 16), 256, 0, stream>>>(WO, Wot);
    prep_bias<<<4, 256, 0, stream>>>(bQ, bK, bV, omega, bQf, bkv);
    // 3. fold omega into WQ/WK (single M=2048 GEMM, outputs transposed into Bt layout)
    gemm_fold<<<dim3(8, 16), 256, 0, stream>>>(WQKb, obdT, Wqt, Wkvt);
    // 4. projections: Q (relu+eps), K|V merged (K relu+eps transposed, V linear transposed)
    gemm256<1><<<256, 512, 0, stream>>>(xb, Wqt, bQf, Qphi, nullptr, 16384, 1024, 1024, 4);
    gemm256<3><<<512, 512, 0, stream>>>(yb, Wkvt, bkv, KphiT, Vt, 16384, 2048, 1024, 8);
    // 5. per-head reductions
    ksum_kernel<<<1024, 256, 0, stream>>>(KphiT, ksum);
    kvt_kernel<<<dim3(4, 64), 256, 0, stream>>>(Vt, KphiT, kvpart);
    // 6. numerator / denominator / divide (kvreduce fused)
    numdiv_kernel<<<dim3(64, 16), 256, 0, stream>>>(Qphi, kvpart, ksum, U);
    // 7. output projection
    gemm256<2><<<256, 512, 0, stream>>>(U, Wot, bO, d_out, nullptr, 16384, 1024, 1024, 4);
}

// Round 6
// 287.464 us; speedup vs baseline: 1.0018x; 1.0018x over previous
//
#include <hip/hip_runtime.h>

#define EPSF 1e-6f

typedef _Float16 f16x8 __attribute__((ext_vector_type(8)));
typedef _Float16 f16x4 __attribute__((ext_vector_type(4)));
typedef float    f32x4 __attribute__((ext_vector_type(4)));
typedef float    f32x16 __attribute__((ext_vector_type(16)));

#define GLL16(gp, lp) __builtin_amdgcn_global_load_lds( \
    (const __attribute__((address_space(1))) void*)(gp), \
    (__attribute__((address_space(3))) void*)(lp), 16, 0, 0)

// ---------------- f32 -> f16 convert, two tensors in one dispatch ----------------
// grid MUST cover 2*n8each threads (one 8-elem item per thread, no stride loop)
__global__ __launch_bounds__(256) void cvt2_f16(const float* __restrict__ inA,
                                                _Float16* __restrict__ outA,
                                                const float* __restrict__ inB,
                                                _Float16* __restrict__ outB, int n8each) {
    int idx = blockIdx.x * 256 + threadIdx.x;
    const float* in = inA; _Float16* out = outA;
    if (idx >= n8each) { idx -= n8each; in = inB; out = outB; }
    const float4* p = (const float4*)in + (size_t)idx * 2;
    float4 a = p[0], b = p[1];
    f16x8 o;
    o[0] = (_Float16)a.x; o[1] = (_Float16)a.y; o[2] = (_Float16)a.z; o[3] = (_Float16)a.w;
    o[4] = (_Float16)b.x; o[5] = (_Float16)b.y; o[6] = (_Float16)b.z; o[7] = (_Float16)b.w;
    *(f16x8*)(out + (size_t)idx * 8) = o;
}

// ---------------- prep: block-diag omega^T (f16) + folded biases, one dispatch ----------------
__global__ __launch_bounds__(256) void prep_all(const float* __restrict__ omega,
                                                const float* __restrict__ bQ,
                                                const float* __restrict__ bK,
                                                const float* __restrict__ bV,
                                                _Float16* __restrict__ obdT,
                                                float* __restrict__ bQf,
                                                float* __restrict__ bkv) {
    int idx = blockIdx.x * 256 + threadIdx.x;   // over 1M
    int c = idx >> 10, k = idx & 1023;
    float v = ((c >> 6) == (k >> 6)) ? omega[(k & 63) * 64 + (c & 63)] : 0.f;
    obdT[idx] = (_Float16)v;
    if (idx < 1024) {
        int h = idx >> 6, e = idx & 63;
        float sq = 0.f, sk = 0.f;
        for (int d = 0; d < 64; d++) {
            float o = omega[d * 64 + e];
            sq += bQ[h * 64 + d] * o;
            sk += bK[h * 64 + d] * o;
        }
        bQf[idx] = sq;
        bkv[idx] = sk;
        bkv[1024 + idx] = bV[idx];
    }
}

// ---------------- transpose 1024x1024 f32 -> f16 ----------------
__global__ __launch_bounds__(256) void transpose_cvt(const float* __restrict__ in,
                                                     _Float16* __restrict__ out) {
    __shared__ float tile[64][65];
    const int t = threadIdx.x;
    const int k0 = blockIdx.x * 64, n0 = blockIdx.y * 64;
#pragma unroll
    for (int j = 0; j < 16; j++) {
        int idx = j * 256 + t; int r = idx >> 6, c = idx & 63;
        tile[r][c] = in[(size_t)(k0 + r) * 1024 + n0 + c];
    }
    __syncthreads();
#pragma unroll
    for (int j = 0; j < 16; j++) {
        int idx = j * 256 + t; int rn = idx >> 6, ck = idx & 63;
        out[(size_t)(n0 + rn) * 1024 + k0 + ck] = (_Float16)tile[ck][rn];
    }
}

// ---------------- fold GEMM (m97 128^2 structure): [WQ;WK](2048x1024) @ obdT^T ----------------
__global__ __launch_bounds__(256) void gemm_fold(const _Float16* __restrict__ A,
                                                 const _Float16* __restrict__ Bt,
                                                 _Float16* __restrict__ out0,
                                                 _Float16* __restrict__ out1) {
    const int K = 1024;
    __shared__ __align__(16) _Float16 Asm[128 * 32];
    __shared__ __align__(16) _Float16 Bsm[128 * 32];
    const int t = threadIdx.x, lane = t & 63, w = t >> 6;
    const int bm = blockIdx.y * 128, bn = blockIdx.x * 128;
    const int wm = (w >> 1) * 64, wn = (w & 1) * 64;
    const int r15 = lane & 15, slog = lane >> 4;

    int aoff[4], boff[4];
#pragma unroll
    for (int m = 0; m < 4; m++) {
        int ra = wm + m * 16 + r15;
        aoff[m] = ra * 32 + (slog ^ ((ra >> 1) & 3)) * 8;
        int rb = wn + m * 16 + r15;
        boff[m] = rb * 32 + (slog ^ ((rb >> 1) & 3)) * 8;
    }
    f32x4 acc[4][4];
#pragma unroll
    for (int m = 0; m < 4; m++)
#pragma unroll
        for (int n = 0; n < 4; n++) acc[m][n] = (f32x4){0.f, 0.f, 0.f, 0.f};

    for (int kt = 0; kt < K; kt += 32) {
        __syncthreads();
#pragma unroll
        for (int i = 0; i < 2; i++) {
            int seg = i * 256 + w * 64 + lane;
            int r = seg >> 2, sp = seg & 3;
            int sg = sp ^ ((r >> 1) & 3);
            GLL16(A  + (size_t)(bm + r) * K + kt + sg * 8, Asm + (size_t)(i * 256 + w * 64) * 8);
            GLL16(Bt + (size_t)(bn + r) * K + kt + sg * 8, Bsm + (size_t)(i * 256 + w * 64) * 8);
        }
        __syncthreads();
        f16x8 av[4], bv[4];
#pragma unroll
        for (int m = 0; m < 4; m++) av[m] = *(const f16x8*)(Asm + aoff[m]);
#pragma unroll
        for (int n = 0; n < 4; n++) bv[n] = *(const f16x8*)(Bsm + boff[n]);
#pragma unroll
        for (int m = 0; m < 4; m++)
#pragma unroll
            for (int n = 0; n < 4; n++)
                acc[m][n] = __builtin_amdgcn_mfma_f32_16x16x32_f16(av[m], bv[n], acc[m][n], 0, 0, 0);
    }

#pragma unroll
    for (int m = 0; m < 4; m++) {
        int row0 = bm + wm + m * 16 + slog * 4;
        _Float16* C = (row0 < 1024) ? out0 : out1;
        int l = row0 & 1023;
#pragma unroll
        for (int n = 0; n < 4; n++) {
            int colg = bn + wn + n * 16 + r15;
            f16x4 p;
#pragma unroll
            for (int j = 0; j < 4; j++) p[j] = (_Float16)acc[m][n][j];
            *(f16x4*)(C + (size_t)colg * 1024 + l) = p;
        }
    }
}

// ---------------- big GEMM: 256x256 tile, BK=32 slab, 4-slab ring, 32x32x16 MFMA ----------------
// LDS ring: 4 slabs x 32KB { A 256x32 f16 @ +0, B 256x32 f16 @ +16384 }.
// Slab row = 64 B; phys 16B slot = (logical_slot + (row>>1)) & 3 (rotate swizzle).
// R3-verified schedule: per slab {counted vmcnt; barrier; stage(s+3); 12 ds_read_b128;
// setprio; 16 MFMA (32x32x16); setprio}. vmcnt never 0 mid-loop.
// C/D layout (m74/m101): col=lane&31, row=(reg&3)+8*(reg>>2)+4*(lane>>5).
// EPI: 1 = relu+eps -> f16 [M][N];  2 = linear -> f32 [M][N];
//      3 = split transposed (col<1024: relu+eps -> out0 [head][d][l]; else linear -> out1)
template<int EPI>
__global__ __launch_bounds__(512, 2) void gemm256(const _Float16* __restrict__ A,
                                                  const _Float16* __restrict__ Bt,
                                                  const float* __restrict__ bias,
                                                  void* __restrict__ out0,
                                                  void* __restrict__ out1,
                                                  int M, int N, int K, int nbn) {
    __shared__ __align__(16) char lds[131072];
    const int t = threadIdx.x, lane = t & 63, w = t >> 6;
    const int nwg = gridDim.x;
    const int f = (blockIdx.x & 7) * (nwg >> 3) + (blockIdx.x >> 3);   // bijective XCD swizzle
    const int bm = (f / nbn) * 256, bn = (f % nbn) * 256;
    const int wm = (w & 1) * 128, wn = (w >> 1) * 64;
    const int l31 = lane & 31, hi2 = lane >> 5;
    const int r15 = lane & 15, hi4 = lane >> 4;
    const int srow = lane >> 2, sp = lane & 3;     // staging: 16 rows/gll, 4 slots/row

    // ds_read byte offsets within a slab: A frag (mf, ks), B frag (nf, ks)
    int aoff[4][2], boff[2][2];
#pragma unroll
    for (int mf = 0; mf < 4; mf++) {
        int r = wm + mf * 32 + l31;
#pragma unroll
        for (int ks = 0; ks < 2; ks++)
            aoff[mf][ks] = r * 64 + (((ks * 2 + hi2 + (r >> 1)) & 3) << 4);
    }
#pragma unroll
    for (int nf = 0; nf < 2; nf++) {
        int r = wn + nf * 32 + l31;
#pragma unroll
        for (int ks = 0; ks < 2; ks++)
            boff[nf][ks] = r * 64 + (((ks * 2 + hi2 + (r >> 1)) & 3) << 4);
    }

    f32x16 acc[4][2];
#pragma unroll
    for (int mf = 0; mf < 4; mf++)
#pragma unroll
        for (int nf = 0; nf < 2; nf++)
#pragma unroll
            for (int j = 0; j < 16; j++) acc[mf][nf][j] = 0.f;

    auto stage = [&](int s) {
        char* base = lds + (s & 3) * 32768;
        int kt = s * 32;
#pragma unroll
        for (int p = 0; p < 2; p++) {
            int row = w * 32 + p * 16 + srow;
            int sg = (sp - ((row >> 1) & 3)) & 3;   // pre-swizzled global slot
            GLL16(A  + (size_t)(bm + row) * K + kt + sg * 8, base + w * 2048 + p * 1024);
            GLL16(Bt + (size_t)(bn + row) * K + kt + sg * 8, base + 16384 + w * 2048 + p * 1024);
        }
    };

    const int NS = K >> 5;
    stage(0); stage(1); stage(2);
    for (int s = 0; s < NS; ++s) {
        if (s + 2 < NS)      asm volatile("s_waitcnt vmcnt(8)" ::: "memory");
        else if (s + 1 < NS) asm volatile("s_waitcnt vmcnt(4)" ::: "memory");
        else                 asm volatile("s_waitcnt vmcnt(0)" ::: "memory");
        asm volatile("s_barrier" ::: "memory");
        if (s + 3 < NS) stage(s + 3);               // slot (s-1)&3: reads done last slab
        const char* La = lds + (s & 3) * 32768;
        const char* Lb = La + 16384;
        f16x8 bv[2][2], av[4][2];
#pragma unroll
        for (int nf = 0; nf < 2; nf++)
#pragma unroll
            for (int ks = 0; ks < 2; ks++) bv[nf][ks] = *(const f16x8*)(Lb + boff[nf][ks]);
#pragma unroll
        for (int mf = 0; mf < 4; mf++)
#pragma unroll
            for (int ks = 0; ks < 2; ks++) av[mf][ks] = *(const f16x8*)(La + aoff[mf][ks]);
        __builtin_amdgcn_s_setprio(1);
#pragma unroll
        for (int mf = 0; mf < 4; mf++)
#pragma unroll
            for (int nf = 0; nf < 2; nf++)
#pragma unroll
                for (int ks = 0; ks < 2; ks++)
                    acc[mf][nf] = __builtin_amdgcn_mfma_f32_32x32x16_f16(av[mf][ks], bv[nf][ks], acc[mf][nf], 0, 0, 0);
        __builtin_amdgcn_s_setprio(0);
    }

    if (EPI == 3) {
        // transposed epilogue via per-wave LDS tile [d=64][l=128] f16 (16 KB), swizzled
        asm volatile("s_barrier" ::: "memory");     // all slab reads done before LDS reuse
        char* LW = lds + w * 16384;
        const int colg0 = bn + wn;
        const bool isK = colg0 < 1024;
        _Float16* Cb = isK ? (_Float16*)out0 : (_Float16*)out1;
        const int hd = (isK ? colg0 : colg0 - 1024) >> 6;
        const int nb = bm >> 12;
        const int l0 = (bm & 4095) + wm;
#pragma unroll
        for (int mf = 0; mf < 4; mf++)
#pragma unroll
            for (int nf = 0; nf < 2; nf++) {
                int dl = nf * 32 + l31;
                float bs = bias[colg0 + dl];
#pragma unroll
                for (int g = 0; g < 4; g++) {
                    f16x4 pk;
#pragma unroll
                    for (int j = 0; j < 4; j++) {
                        float xv = acc[mf][nf][g * 4 + j] + bs;
                        if (isK) xv = fmaxf(xv, 0.f) + EPSF;
                        pk[j] = (_Float16)xv;
                    }
                    int lby = mf * 64 + g * 16 + hi2 * 8;   // byte offset along l
                    *(f16x4*)(LW + dl * 256 + (lby ^ ((dl & 15) << 4))) = pk;
                }
            }
        _Float16* basep = Cb + (size_t)(nb * 16 + hd) * 64 * 4096 + l0;
#pragma unroll
        for (int pass = 0; pass < 16; pass++) {
            int d = pass * 4 + hi4;
            f16x8 v = *(const f16x8*)(LW + d * 256 + ((r15 * 16) ^ ((d & 15) << 4)));
            *(f16x8*)(basep + (size_t)d * 4096 + r15 * 8) = v;
        }
    } else {
#pragma unroll
        for (int mf = 0; mf < 4; mf++)
#pragma unroll
            for (int nf = 0; nf < 2; nf++) {
                int colg = bn + wn + nf * 32 + l31;
                float bs = bias ? bias[colg] : 0.f;
#pragma unroll
                for (int g = 0; g < 4; g++) {
                    int row0 = bm + wm + mf * 32 + 8 * g + 4 * hi2;
#pragma unroll
                    for (int j = 0; j < 4; j++) {
                        float xv = acc[mf][nf][g * 4 + j] + bs;
                        if (EPI == 1) {
                            xv = fmaxf(xv, 0.f) + EPSF;
                            ((_Float16*)out0)[(size_t)(row0 + j) * N + colg] = (_Float16)xv;
                        } else {
                            ((float*)out0)[(size_t)(row0 + j) * N + colg] = xv;
                        }
                    }
                }
            }
    }
}

// ---------------- ksum[head][d] = sum_l KphiT[head][d][l] ----------------
__global__ __launch_bounds__(256) void ksum_kernel(const _Float16* __restrict__ KphiT,
                                                   float* __restrict__ ksum) {
    const int t = threadIdx.x, lane = t & 63, w = t >> 6;
    const int gid = blockIdx.x;          // 0..1023
    const int head = gid >> 4;
    const int d = (gid & 15) * 4 + w;
    const _Float16* src = KphiT + ((size_t)head * 64 + d) * 4096;
    float s = 0.f;
#pragma unroll
    for (int i = 0; i < 8; i++) {
        f16x8 v = *(const f16x8*)(src + (size_t)(i * 64 + lane) * 8);
#pragma unroll
        for (int j = 0; j < 8; j++) s += (float)v[j];
    }
#pragma unroll
    for (int o = 32; o; o >>= 1) s += __shfl_xor(s, o, 64);
    if (lane == 0) ksum[(size_t)head * 64 + d] = s;
}

// ---------------- kv partials ----------------
__global__ __launch_bounds__(256) void kvt_kernel(const _Float16* __restrict__ Vt,
                                                  const _Float16* __restrict__ KphiT,
                                                  float* __restrict__ kvpart) {
    const int t = threadIdx.x, lane = t & 63, w = t >> 6;
    const int head = blockIdx.y;
    const int l0 = blockIdx.x * 1024;
    __shared__ __align__(16) _Float16 As[64 * 128];
    __shared__ __align__(16) _Float16 Bs[64 * 128];
    const int r15 = lane & 15, slog = lane >> 4;
    f32x4 acc[4][4];
#pragma unroll
    for (int m = 0; m < 4; m++)
#pragma unroll
        for (int n = 0; n < 4; n++) acc[m][n] = (f32x4){0.f, 0.f, 0.f, 0.f};

    for (int it = 0; it < 8; it++) {
        __syncthreads();
        int lbase = l0 + it * 128;
#pragma unroll
        for (int i = 0; i < 4; i++) {
            int seg = i * 256 + w * 64 + lane;
            int r = seg >> 4, sp2 = seg & 15;
            int sg = sp2 ^ (r & 15);
            GLL16(Vt    + ((size_t)head * 64 + r) * 4096 + lbase + sg * 8, As + (size_t)(i * 256 + w * 64) * 8);
            GLL16(KphiT + ((size_t)head * 64 + r) * 4096 + lbase + sg * 8, Bs + (size_t)(i * 256 + w * 64) * 8);
        }
        __syncthreads();
        f16x8 av[4], bv[4];
#pragma unroll
        for (int m = 0; m < 4; m++) {
            int r = m * 16 + r15;
            int s2 = w * 4 + slog;
            int ph = s2 ^ (r & 15);
            av[m] = *(const f16x8*)(As + r * 128 + ph * 8);
            bv[m] = *(const f16x8*)(Bs + r * 128 + ph * 8);
        }
#pragma unroll
        for (int m = 0; m < 4; m++)
#pragma unroll
            for (int n = 0; n < 4; n++)
                acc[m][n] = __builtin_amdgcn_mfma_f32_16x16x32_f16(av[m], bv[n], acc[m][n], 0, 0, 0);
    }
    float* red = (float*)As;
    for (int ww = 0; ww < 4; ww++) {
        __syncthreads();
        if (w == ww) {
#pragma unroll
            for (int m = 0; m < 4; m++)
#pragma unroll
                for (int n = 0; n < 4; n++)
#pragma unroll
                    for (int j = 0; j < 4; j++) {
                        int row = m * 16 + slog * 4 + j, col = n * 16 + r15;
                        if (ww == 0) red[row * 64 + col] = acc[m][n][j];
                        else         red[row * 64 + col] += acc[m][n][j];
                    }
        }
    }
    __syncthreads();
    float* outp = kvpart + ((size_t)head * 4 + blockIdx.x) * 4096;
#pragma unroll
    for (int i = 0; i < 16; i++) { int idx = i * 256 + t; outp[idx] = red[idx]; }
}

// ---------------- numerator GEMM + denominator + divide -> U (f16); kvreduce fused ----------------
__global__ __launch_bounds__(256) void numdiv_kernel(const _Float16* __restrict__ Qphi,
                                                     const float* __restrict__ kvpart,
                                                     const float* __restrict__ ksum,
                                                     _Float16* __restrict__ U) {
    const int t = threadIdx.x, lane = t & 63, w = t >> 6;
    const int h = blockIdx.y;
    const int m0 = blockIdx.x * 256;
    const int nb = m0 >> 12;
    const int head = nb * 16 + h;
    __shared__ __align__(16) _Float16 Qs[256 * 64];
    __shared__ __align__(16) _Float16 Bs[64 * 64];
    __shared__ float ksl[64];

#pragma unroll
    for (int i = 0; i < 8; i++) {
        int seg = i * 256 + w * 64 + lane;
        int r = seg >> 3, sp = seg & 7;
        int sg = sp ^ (r & 7);
        GLL16(Qphi + (size_t)(m0 + r) * 1024 + h * 64 + sg * 8, Qs + (size_t)(i * 256 + w * 64) * 8);
    }
#pragma unroll
    for (int i = 0; i < 2; i++) {
        int sidx = i * 256 + t;
        int r = sidx >> 3, p = sidx & 7;
        int sg = p ^ (r & 7);
        const float* s0 = kvpart + (size_t)head * 4 * 4096 + r * 64 + sg * 8;
        float4 v0 = {0.f, 0.f, 0.f, 0.f}, v1 = {0.f, 0.f, 0.f, 0.f};
#pragma unroll
        for (int c = 0; c < 4; c++) {
            float4 a = *(const float4*)(s0 + c * 4096);
            float4 b = *(const float4*)(s0 + c * 4096 + 4);
            v0.x += a.x; v0.y += a.y; v0.z += a.z; v0.w += a.w;
            v1.x += b.x; v1.y += b.y; v1.z += b.z; v1.w += b.w;
        }
        f16x8 o;
        o[0] = (_Float16)v0.x; o[1] = (_Float16)v0.y; o[2] = (_Float16)v0.z; o[3] = (_Float16)v0.w;
        o[4] = (_Float16)v1.x; o[5] = (_Float16)v1.y; o[6] = (_Float16)v1.z; o[7] = (_Float16)v1.w;
        *(f16x8*)(Bs + sidx * 8) = o;
    }
    if (t < 64) ksl[t] = ksum[(size_t)head * 64 + t];
    __syncthreads();

    const int r15 = lane & 15, slog = lane >> 4;
    f32x4 acc[4][4];
#pragma unroll
    for (int m = 0; m < 4; m++)
#pragma unroll
        for (int n = 0; n < 4; n++) acc[m][n] = (f32x4){0.f, 0.f, 0.f, 0.f};
    float dp[4] = {0.f, 0.f, 0.f, 0.f};

#pragma unroll
    for (int kk = 0; kk < 2; kk++) {
        float ks[8];
#pragma unroll
        for (int j = 0; j < 8; j++) ks[j] = ksl[kk * 32 + slog * 8 + j];
        f16x8 av[4], bv[4];
#pragma unroll
        for (int m = 0; m < 4; m++) {
            int r = w * 64 + m * 16 + r15;
            int ph = (kk * 4 + slog) ^ (r & 7);
            av[m] = *(const f16x8*)(Qs + r * 64 + ph * 8);
        }
#pragma unroll
        for (int n = 0; n < 4; n++) {
            int r = n * 16 + r15;
            int ph = (kk * 4 + slog) ^ (r & 7);
            bv[n] = *(const f16x8*)(Bs + r * 64 + ph * 8);
        }
#pragma unroll
        for (int m = 0; m < 4; m++)
#pragma unroll
            for (int j = 0; j < 8; j++) dp[m] += (float)av[m][j] * ks[j];
#pragma unroll
        for (int m = 0; m < 4; m++)
#pragma unroll
            for (int n = 0; n < 4; n++)
                acc[m][n] = __builtin_amdgcn_mfma_f32_16x16x32_f16(av[m], bv[n], acc[m][n], 0, 0, 0);
    }
#pragma unroll
    for (int m = 0; m < 4; m++) {
        dp[m] += __shfl_xor(dp[m], 16, 64);
        dp[m] += __shfl_xor(dp[m], 32, 64);
    }
#pragma unroll
    for (int m = 0; m < 4; m++) {
#pragma unroll
        for (int j = 0; j < 4; j++) {
            float den = __shfl(dp[m], slog * 4 + j, 64);
            float inv = __builtin_amdgcn_rcpf(den);
            int row = m0 + w * 64 + m * 16 + slog * 4 + j;
#pragma unroll
            for (int n = 0; n < 4; n++)
                U[(size_t)row * 1024 + h * 64 + n * 16 + r15] = (_Float16)(acc[m][n][j] * inv);
        }
    }
}

// ------------------------------------------------------------------------------------
extern "C" void kernel_launch(void* const* d_in, const int* in_sizes, int n_in,
                              void* d_out, int out_size, void* d_ws, size_t ws_size,
                              hipStream_t stream) {
    (void)in_sizes; (void)n_in; (void)out_size; (void)ws_size;
    const float* x     = (const float*)d_in[0];
    const float* y     = (const float*)d_in[1];
    const float* WQ    = (const float*)d_in[2];
    const float* bQ    = (const float*)d_in[3];
    const float* WK    = (const float*)d_in[4];
    const float* bK    = (const float*)d_in[5];
    const float* WV    = (const float*)d_in[6];
    const float* bV    = (const float*)d_in[7];
    const float* WO    = (const float*)d_in[8];
    const float* bO    = (const float*)d_in[9];
    const float* omega = (const float*)d_in[10];

    char* ws = (char*)d_ws;
    size_t off = 0;
    auto alloc = [&](size_t bytes) { void* p = ws + off; off += (bytes + 255) & ~(size_t)255; return p; };
    const size_t BIG = (size_t)16384 * 1024 * 2;    // 32 MiB f16
    _Float16* xb    = (_Float16*)alloc(BIG);        // reused for U later
    _Float16* yb    = (_Float16*)alloc(BIG);
    _Float16* WQKb  = (_Float16*)alloc((size_t)2048 * 1024 * 2);  // stacked WQ;WK f16
    _Float16* obdT  = (_Float16*)alloc(1024 * 1024 * 2);
    _Float16* Wqt   = (_Float16*)alloc(1024 * 1024 * 2);
    _Float16* Wkvt  = (_Float16*)alloc((size_t)2048 * 1024 * 2);  // rows 0-1023: K-fold, 1024-2047: V^T
    _Float16* Wot   = (_Float16*)alloc(1024 * 1024 * 2);
    float*    bQf   = (float*)alloc(1024 * 4);
    float*    bkv   = (float*)alloc(2048 * 4);
    _Float16* Qphi  = (_Float16*)alloc(BIG);
    _Float16* KphiT = (_Float16*)alloc(BIG);
    _Float16* Vt    = (_Float16*)alloc(BIG);
    float*    kvpart= (float*)alloc((size_t)256 * 4096 * 4);
    float*    ksum  = (float*)alloc((size_t)64 * 64 * 4);
    _Float16* U     = xb;  // alias: xb dead after Qphi GEMM

    // 1. precision converts (x and y in one dispatch; WQ/WK stacked in one)
    // grid covers 2*n8each threads exactly (no stride loop!)
    cvt2_f16<<<16384, 256, 0, stream>>>(x, xb, y, yb, 16384 * 1024 / 8);
    cvt2_f16<<<1024, 256, 0, stream>>>(WQ, WQKb, WK, WQKb + (size_t)1024 * 1024, 1024 * 1024 / 8);
    // 2. omega block-diag (transposed) + bias folds (one dispatch) + weight transposes
    prep_all<<<4096, 256, 0, stream>>>(omega, bQ, bK, bV, obdT, bQf, bkv);
    transpose_cvt<<<dim3(16, 16), 256, 0, stream>>>(WV, Wkvt + (size_t)1024 * 1024);
    transpose_cvt<<<dim3(16, 16), 256, 0, stream>>>(WO, Wot);
    // 3. fold omega into WQ/WK (single M=2048 GEMM, outputs transposed into Bt layout)
    gemm_fold<<<dim3(8, 16), 256, 0, stream>>>(WQKb, obdT, Wqt, Wkvt);
    // 4. projections: Q (relu+eps), K|V merged (K relu+eps transposed, V linear transposed)
    gemm256<1><<<256, 512, 0, stream>>>(xb, Wqt, bQf, Qphi, nullptr, 16384, 1024, 1024, 4);
    gemm256<3><<<512, 512, 0, stream>>>(yb, Wkvt, bkv, KphiT, Vt, 16384, 2048, 1024, 8);
    // 5. per-head reductions
    ksum_kernel<<<1024, 256, 0, stream>>>(KphiT, ksum);
    kvt_kernel<<<dim3(4, 64), 256, 0, stream>>>(Vt, KphiT, kvpart);
    // 6. numerator / denominator / divide (kvreduce fused)
    numdiv_kernel<<<dim3(64, 16), 256, 0, stream>>>(Qphi, kvpart, ksum, U);
    // 7. output projection
    gemm256<2><<<256, 512, 0, stream>>>(U, Wot, bO, d_out, nullptr, 16384, 1024, 1024, 4);
}

// Round 7
// 280.184 us; speedup vs baseline: 1.0278x; 1.0260x over previous
//
#include <hip/hip_runtime.h>

#define EPSF 1e-6f

typedef _Float16 f16x8 __attribute__((ext_vector_type(8)));
typedef _Float16 f16x4 __attribute__((ext_vector_type(4)));
typedef float    f32x4 __attribute__((ext_vector_type(4)));

#define GLL16(gp, lp) __builtin_amdgcn_global_load_lds( \
    (const __attribute__((address_space(1))) void*)(gp), \
    (__attribute__((address_space(3))) void*)(lp), 16, 0, 0)

// ---------------- f32 -> f16 convert, two tensors in one dispatch ----------------
// grid MUST cover 2*n8each threads (one 8-elem item per thread)
__global__ __launch_bounds__(256) void cvt2_f16(const float* __restrict__ inA,
                                                _Float16* __restrict__ outA,
                                                const float* __restrict__ inB,
                                                _Float16* __restrict__ outB, int n8each) {
    int idx = blockIdx.x * 256 + threadIdx.x;
    const float* in = inA; _Float16* out = outA;
    if (idx >= n8each) { idx -= n8each; in = inB; out = outB; }
    const float4* p = (const float4*)in + (size_t)idx * 2;
    float4 a = p[0], b = p[1];
    f16x8 o;
    o[0] = (_Float16)a.x; o[1] = (_Float16)a.y; o[2] = (_Float16)a.z; o[3] = (_Float16)a.w;
    o[4] = (_Float16)b.x; o[5] = (_Float16)b.y; o[6] = (_Float16)b.z; o[7] = (_Float16)b.w;
    *(f16x8*)(out + (size_t)idx * 8) = o;
}

// ---------------- prep: block-diag omega^T (f16) + folded biases + ksum zero ----------------
__global__ __launch_bounds__(256) void prep_all(const float* __restrict__ omega,
                                                const float* __restrict__ bQ,
                                                const float* __restrict__ bK,
                                                const float* __restrict__ bV,
                                                _Float16* __restrict__ obdT,
                                                float* __restrict__ bQf,
                                                float* __restrict__ bkv,
                                                float* __restrict__ ksum) {
    int idx = blockIdx.x * 256 + threadIdx.x;   // over 1M
    int c = idx >> 10, k = idx & 1023;
    float v = ((c >> 6) == (k >> 6)) ? omega[(k & 63) * 64 + (c & 63)] : 0.f;
    obdT[idx] = (_Float16)v;
    if (idx < 4096) ksum[idx] = 0.f;            // zeroed every call (atomics target)
    if (idx < 1024) {
        int h = idx >> 6, e = idx & 63;
        float sq = 0.f, sk = 0.f;
        for (int d = 0; d < 64; d++) {
            float o = omega[d * 64 + e];
            sq += bQ[h * 64 + d] * o;
            sk += bK[h * 64 + d] * o;
        }
        bQf[idx] = sq;
        bkv[idx] = sk;
        bkv[1024 + idx] = bV[idx];
    }
}

// ---------------- transpose 1024x1024 f32 -> f16 ----------------
__global__ __launch_bounds__(256) void transpose_cvt(const float* __restrict__ in,
                                                     _Float16* __restrict__ out) {
    __shared__ float tile[64][65];
    const int t = threadIdx.x;
    const int k0 = blockIdx.x * 64, n0 = blockIdx.y * 64;
#pragma unroll
    for (int j = 0; j < 16; j++) {
        int idx = j * 256 + t; int r = idx >> 6, c = idx & 63;
        tile[r][c] = in[(size_t)(k0 + r) * 1024 + n0 + c];
    }
    __syncthreads();
#pragma unroll
    for (int j = 0; j < 16; j++) {
        int idx = j * 256 + t; int rn = idx >> 6, ck = idx & 63;
        out[(size_t)(n0 + rn) * 1024 + k0 + ck] = (_Float16)tile[ck][rn];
    }
}

// ---------------- fold GEMM (m97 128^2 structure): [WQ;WK](2048x1024) @ obdT^T ----------------
__global__ __launch_bounds__(256) void gemm_fold(const _Float16* __restrict__ A,
                                                 const _Float16* __restrict__ Bt,
                                                 _Float16* __restrict__ out0,
                                                 _Float16* __restrict__ out1) {
    const int K = 1024;
    __shared__ __align__(16) _Float16 Asm[128 * 32];
    __shared__ __align__(16) _Float16 Bsm[128 * 32];
    const int t = threadIdx.x, lane = t & 63, w = t >> 6;
    const int bm = blockIdx.y * 128, bn = blockIdx.x * 128;
    const int wm = (w >> 1) * 64, wn = (w & 1) * 64;
    const int r15 = lane & 15, slog = lane >> 4;

    int aoff[4], boff[4];
#pragma unroll
    for (int m = 0; m < 4; m++) {
        int ra = wm + m * 16 + r15;
        aoff[m] = ra * 32 + (slog ^ ((ra >> 1) & 3)) * 8;
        int rb = wn + m * 16 + r15;
        boff[m] = rb * 32 + (slog ^ ((rb >> 1) & 3)) * 8;
    }
    f32x4 acc[4][4];
#pragma unroll
    for (int m = 0; m < 4; m++)
#pragma unroll
        for (int n = 0; n < 4; n++) acc[m][n] = (f32x4){0.f, 0.f, 0.f, 0.f};

    for (int kt = 0; kt < K; kt += 32) {
        __syncthreads();
#pragma unroll
        for (int i = 0; i < 2; i++) {
            int seg = i * 256 + w * 64 + lane;
            int r = seg >> 2, sp = seg & 3;
            int sg = sp ^ ((r >> 1) & 3);
            GLL16(A  + (size_t)(bm + r) * K + kt + sg * 8, Asm + (size_t)(i * 256 + w * 64) * 8);
            GLL16(Bt + (size_t)(bn + r) * K + kt + sg * 8, Bsm + (size_t)(i * 256 + w * 64) * 8);
        }
        __syncthreads();
        f16x8 av[4], bv[4];
#pragma unroll
        for (int m = 0; m < 4; m++) av[m] = *(const f16x8*)(Asm + aoff[m]);
#pragma unroll
        for (int n = 0; n < 4; n++) bv[n] = *(const f16x8*)(Bsm + boff[n]);
#pragma unroll
        for (int m = 0; m < 4; m++)
#pragma unroll
            for (int n = 0; n < 4; n++)
                acc[m][n] = __builtin_amdgcn_mfma_f32_16x16x32_f16(av[m], bv[n], acc[m][n], 0, 0, 0);
    }

#pragma unroll
    for (int m = 0; m < 4; m++) {
        int row0 = bm + wm + m * 16 + slog * 4;
        _Float16* C = (row0 < 1024) ? out0 : out1;
        int l = row0 & 1023;
#pragma unroll
        for (int n = 0; n < 4; n++) {
            int colg = bn + wn + n * 16 + r15;
            f16x4 p;
#pragma unroll
            for (int j = 0; j < 4; j++) p[j] = (_Float16)acc[m][n][j];
            *(f16x4*)(C + (size_t)colg * 1024 + l) = p;
        }
    }
}

// ---------------- big GEMM: 256x256 tile, BK=32 slab, 4-slab ring, 16x16x32 MFMA ----------------
// (R3-verified core: counted vmcnt, 1 barrier/slab, rotate swizzle, 32 MFMA/slab/wave)
// EPI: 2 = linear -> f32 [M][N], Bt batched per 4096 rows (out0)
//      3 = split transposed (col<1024: relu+eps -> out0 [head][d][l] + ksum atomics; else linear -> out1)
//      4 = relu+eps, fused divide by (qphi . ksum): writes U2 = qphi*4096/den -> f16 out0; out1 = ksum
template<int EPI>
__global__ __launch_bounds__(512, 2) void gemm256(const _Float16* __restrict__ A,
                                                  const _Float16* __restrict__ Bt,
                                                  const float* __restrict__ bias,
                                                  void* __restrict__ out0,
                                                  void* __restrict__ out1,
                                                  float* __restrict__ ksum,
                                                  int M, int N, int K, int nbn) {
    __shared__ __align__(16) char lds[131072];
    const int t = threadIdx.x, lane = t & 63, w = t >> 6;
    const int nwg = gridDim.x;
    const int f = (blockIdx.x & 7) * (nwg >> 3) + (blockIdx.x >> 3);   // bijective XCD swizzle
    const int bm = (f / nbn) * 256, bn = (f % nbn) * 256;
    const int wm = (w & 1) * 128, wn = (w >> 1) * 64;
    const int r15 = lane & 15, hi = lane >> 4;
    const int srow = lane >> 2, sp = lane & 3;     // staging: 16 rows/gll, 4 slots/row
    const _Float16* BtU = (EPI == 2) ? Bt + ((size_t)(bm >> 12) << 20) : Bt;  // per-batch B

    int aoff[8], boff[4];
#pragma unroll
    for (int m = 0; m < 8; m++) {
        int r = wm + m * 16 + r15;
        aoff[m] = r * 64 + (((hi + (r >> 1)) & 3) << 4);
    }
#pragma unroll
    for (int n = 0; n < 4; n++) {
        int r = wn + n * 16 + r15;
        boff[n] = r * 64 + (((hi + (r >> 1)) & 3) << 4);
    }

    f32x4 acc[8][4];
#pragma unroll
    for (int m = 0; m < 8; m++)
#pragma unroll
        for (int n = 0; n < 4; n++) acc[m][n] = (f32x4){0.f, 0.f, 0.f, 0.f};

    auto stage = [&](int s) {
        char* base = lds + (s & 3) * 32768;
        int kt = s * 32;
#pragma unroll
        for (int p = 0; p < 2; p++) {
            int row = w * 32 + p * 16 + srow;
            int sg = (sp - ((row >> 1) & 3)) & 3;   // pre-swizzled global slot
            GLL16(A   + (size_t)(bm + row) * K + kt + sg * 8, base + w * 2048 + p * 1024);
            GLL16(BtU + (size_t)(bn + row) * K + kt + sg * 8, base + 16384 + w * 2048 + p * 1024);
        }
    };

    const int NS = K >> 5;
    stage(0); stage(1); stage(2);
    for (int s = 0; s < NS; ++s) {
        if (s + 2 < NS)      asm volatile("s_waitcnt vmcnt(8)" ::: "memory");
        else if (s + 1 < NS) asm volatile("s_waitcnt vmcnt(4)" ::: "memory");
        else                 asm volatile("s_waitcnt vmcnt(0)" ::: "memory");
        asm volatile("s_barrier" ::: "memory");
        if (s + 3 < NS) stage(s + 3);               // slot (s-1)&3: reads done last slab
        const char* La = lds + (s & 3) * 32768;
        const char* Lb = La + 16384;
        f16x8 bv[4];
#pragma unroll
        for (int n = 0; n < 4; n++) bv[n] = *(const f16x8*)(Lb + boff[n]);
        f16x8 av[8];
#pragma unroll
        for (int m = 0; m < 8; m++) av[m] = *(const f16x8*)(La + aoff[m]);
        __builtin_amdgcn_s_setprio(1);
#pragma unroll
        for (int m = 0; m < 8; m++)
#pragma unroll
            for (int n = 0; n < 4; n++)
                acc[m][n] = __builtin_amdgcn_mfma_f32_16x16x32_f16(av[m], bv[n], acc[m][n], 0, 0, 0);
        __builtin_amdgcn_s_setprio(0);
    }

    if (EPI == 3) {
        // transposed epilogue via per-wave LDS tile [d=64][l=128] f16 (16 KB), swizzled
        asm volatile("s_barrier" ::: "memory");     // all slab reads done before LDS reuse
        char* LW = lds + w * 16384;
        const int colg0 = bn + wn;
        const bool isK = colg0 < 1024;
        _Float16* Cb = isK ? (_Float16*)out0 : (_Float16*)out1;
        const int hd = (isK ? colg0 : colg0 - 1024) >> 6;
        const int nb = bm >> 12;
        const int l0 = (bm & 4095) + wm;
        float cs[4] = {0.f, 0.f, 0.f, 0.f};
#pragma unroll
        for (int m = 0; m < 8; m++)
#pragma unroll
            for (int n = 0; n < 4; n++) {
                int d = n * 16 + r15;
                float bs = bias[colg0 + d];
                f16x4 pk;
#pragma unroll
                for (int j = 0; j < 4; j++) {
                    float xv = acc[m][n][j] + bs;
                    if (isK) { xv = fmaxf(xv, 0.f) + EPSF; cs[n] += xv; }
                    pk[j] = (_Float16)xv;
                }
                *(f16x4*)(LW + d * 256 + ((m * 32 + hi * 8) ^ ((d & 15) << 4))) = pk;
            }
        if (isK) {   // fused ksum: reduce 128 rows per wave, atomically add per (head, d)
#pragma unroll
            for (int n = 0; n < 4; n++) {
                cs[n] += __shfl_xor(cs[n], 16, 64);
                cs[n] += __shfl_xor(cs[n], 32, 64);
            }
            if (hi == 0) {
#pragma unroll
                for (int n = 0; n < 4; n++)
                    atomicAdd(ksum + (size_t)(nb * 16 + hd) * 64 + n * 16 + r15, cs[n]);
            }
        }
        _Float16* basep = Cb + (size_t)(nb * 16 + hd) * 64 * 4096 + l0;
#pragma unroll
        for (int pass = 0; pass < 16; pass++) {
            int d = pass * 4 + hi;
            f16x8 v = *(const f16x8*)(LW + d * 256 + ((r15 * 16) ^ ((d & 15) << 4)));
            *(f16x8*)(basep + (size_t)d * 4096 + r15 * 8) = v;
        }
    } else if (EPI == 4) {
        // relu+eps, then divide by den = qphi . ksum[head] (wave owns one head's 64 cols)
        const int headg = (bm >> 12) * 16 + ((bn + wn) >> 6);
        const float* ks = (const float*)out1;
        float ksn[4];
#pragma unroll
        for (int n = 0; n < 4; n++) ksn[n] = ks[(size_t)headg * 64 + n * 16 + r15];
        _Float16* C = (_Float16*)out0;
#pragma unroll
        for (int m = 0; m < 8; m++) {
            int row0 = bm + wm + m * 16 + hi * 4;
            float qv[4][4], dp[4] = {0.f, 0.f, 0.f, 0.f};
#pragma unroll
            for (int n = 0; n < 4; n++) {
                int colg = bn + wn + n * 16 + r15;
                float bs = bias[colg];
#pragma unroll
                for (int j = 0; j < 4; j++) {
                    float xv = fmaxf(acc[m][n][j] + bs, 0.f) + EPSF;
                    qv[n][j] = xv;
                    dp[j] += xv * ksn[n];
                }
            }
#pragma unroll
            for (int j = 0; j < 4; j++) {       // reduce over the 16 r15 lanes
                dp[j] += __shfl_xor(dp[j], 1, 64);
                dp[j] += __shfl_xor(dp[j], 2, 64);
                dp[j] += __shfl_xor(dp[j], 4, 64);
                dp[j] += __shfl_xor(dp[j], 8, 64);
                dp[j] = 4096.0f * __builtin_amdgcn_rcpf(dp[j]);
            }
#pragma unroll
            for (int n = 0; n < 4; n++) {
                int colg = bn + wn + n * 16 + r15;
#pragma unroll
                for (int j = 0; j < 4; j++)
                    C[(size_t)(row0 + j) * N + colg] = (_Float16)(qv[n][j] * dp[j]);
            }
        }
    } else {
#pragma unroll
        for (int m = 0; m < 8; m++) {
            int row0 = bm + wm + m * 16 + hi * 4;
#pragma unroll
            for (int n = 0; n < 4; n++) {
                int colg = bn + wn + n * 16 + r15;
                float bs = bias ? bias[colg] : 0.f;
#pragma unroll
                for (int j = 0; j < 4; j++)
                    ((float*)out0)[(size_t)(row0 + j) * N + colg] = acc[m][n][j] + bs;
            }
        }
    }
}

// ---------------- kv partials: kvpart[head][chunk][e][d] = sum_{l in chunk} V[l][e]*Kphi[l][d] ----------------
__global__ __launch_bounds__(256) void kvt_kernel(const _Float16* __restrict__ Vt,
                                                  const _Float16* __restrict__ KphiT,
                                                  float* __restrict__ kvpart) {
    const int t = threadIdx.x, lane = t & 63, w = t >> 6;
    const int head = blockIdx.y;
    const int l0 = blockIdx.x * 1024;
    __shared__ __align__(16) _Float16 As[64 * 128];
    __shared__ __align__(16) _Float16 Bs[64 * 128];
    const int r15 = lane & 15, slog = lane >> 4;
    f32x4 acc[4][4];
#pragma unroll
    for (int m = 0; m < 4; m++)
#pragma unroll
        for (int n = 0; n < 4; n++) acc[m][n] = (f32x4){0.f, 0.f, 0.f, 0.f};

    for (int it = 0; it < 8; it++) {
        __syncthreads();
        int lbase = l0 + it * 128;
#pragma unroll
        for (int i = 0; i < 4; i++) {
            int seg = i * 256 + w * 64 + lane;
            int r = seg >> 4, sp2 = seg & 15;
            int sg = sp2 ^ (r & 15);
            GLL16(Vt    + ((size_t)head * 64 + r) * 4096 + lbase + sg * 8, As + (size_t)(i * 256 + w * 64) * 8);
            GLL16(KphiT + ((size_t)head * 64 + r) * 4096 + lbase + sg * 8, Bs + (size_t)(i * 256 + w * 64) * 8);
        }
        __syncthreads();
        f16x8 av[4], bv[4];
#pragma unroll
        for (int m = 0; m < 4; m++) {
            int r = m * 16 + r15;
            int s2 = w * 4 + slog;
            int ph = s2 ^ (r & 15);
            av[m] = *(const f16x8*)(As + r * 128 + ph * 8);
            bv[m] = *(const f16x8*)(Bs + r * 128 + ph * 8);
        }
#pragma unroll
        for (int m = 0; m < 4; m++)
#pragma unroll
            for (int n = 0; n < 4; n++)
                acc[m][n] = __builtin_amdgcn_mfma_f32_16x16x32_f16(av[m], bv[n], acc[m][n], 0, 0, 0);
    }
    float* red = (float*)As;
    for (int ww = 0; ww < 4; ww++) {
        __syncthreads();
        if (w == ww) {
#pragma unroll
            for (int m = 0; m < 4; m++)
#pragma unroll
                for (int n = 0; n < 4; n++)
#pragma unroll
                    for (int j = 0; j < 4; j++) {
                        int row = m * 16 + slog * 4 + j, col = n * 16 + r15;
                        if (ww == 0) red[row * 64 + col] = acc[m][n][j];
                        else         red[row * 64 + col] += acc[m][n][j];
                    }
        }
    }
    __syncthreads();
    float* outp = kvpart + ((size_t)head * 4 + blockIdx.x) * 4096;
#pragma unroll
    for (int i = 0; i < 16; i++) { int idx = i * 256 + t; outp[idx] = red[idx]; }
}

// ---------------- W2t[b][j][hl*64+d] = (1/4096) sum_e Wot[j][hl*64+e] * kv[gh][e][d] ----------------
__global__ __launch_bounds__(256) void w2t_kernel(const _Float16* __restrict__ Wot,
                                                  const float* __restrict__ kvpart,
                                                  _Float16* __restrict__ W2t) {
    const int t = threadIdx.x;
    const int jb = blockIdx.x;      // 0..7 (128 j-rows each)
    const int gh = blockIdx.y;      // 0..63 global head
    const int b = gh >> 4, hl = gh & 15;
    __shared__ float kvL[64][65];
    const float* kp = kvpart + (size_t)gh * 4 * 4096;
#pragma unroll
    for (int i = 0; i < 16; i++) {
        int idx = i * 256 + t;
        float s = 0.f;
#pragma unroll
        for (int c = 0; c < 4; c++) s += kp[c * 4096 + idx];
        kvL[idx >> 6][idx & 63] = s;
    }
    __syncthreads();
    const int j = jb * 128 + (t >> 1);
    const int d0 = (t & 1) * 32;
    const _Float16* wr = Wot + (size_t)j * 1024 + hl * 64;
    float wv[64];
#pragma unroll
    for (int i = 0; i < 8; i++) {
        f16x8 v = *(const f16x8*)(wr + i * 8);
#pragma unroll
        for (int k = 0; k < 8; k++) wv[i * 8 + k] = (float)v[k];
    }
    _Float16* outp = W2t + ((size_t)b << 20) + (size_t)j * 1024 + hl * 64 + d0;
#pragma unroll
    for (int d = 0; d < 32; d++) {
        float s = 0.f;
#pragma unroll
        for (int e = 0; e < 64; e++) s += wv[e] * kvL[e][d0 + d];
        outp[d] = (_Float16)(s * (1.0f / 4096.0f));
    }
}

// ------------------------------------------------------------------------------------
extern "C" void kernel_launch(void* const* d_in, const int* in_sizes, int n_in,
                              void* d_out, int out_size, void* d_ws, size_t ws_size,
                              hipStream_t stream) {
    (void)in_sizes; (void)n_in; (void)out_size; (void)ws_size;
    const float* x     = (const float*)d_in[0];
    const float* y     = (const float*)d_in[1];
    const float* WQ    = (const float*)d_in[2];
    const float* bQ    = (const float*)d_in[3];
    const float* WK    = (const float*)d_in[4];
    const float* bK    = (const float*)d_in[5];
    const float* WV    = (const float*)d_in[6];
    const float* bV    = (const float*)d_in[7];
    const float* WO    = (const float*)d_in[8];
    const float* bO    = (const float*)d_in[9];
    const float* omega = (const float*)d_in[10];

    char* ws = (char*)d_ws;
    size_t off = 0;
    auto alloc = [&](size_t bytes) { void* p = ws + off; off += (bytes + 255) & ~(size_t)255; return p; };
    const size_t BIG = (size_t)16384 * 1024 * 2;    // 32 MiB f16
    _Float16* xb    = (_Float16*)alloc(BIG);
    _Float16* yb    = (_Float16*)alloc(BIG);
    _Float16* WQKb  = (_Float16*)alloc((size_t)2048 * 1024 * 2);  // stacked WQ;WK f16
    _Float16* obdT  = (_Float16*)alloc(1024 * 1024 * 2);
    _Float16* Wqt   = (_Float16*)alloc(1024 * 1024 * 2);
    _Float16* Wkvt  = (_Float16*)alloc((size_t)2048 * 1024 * 2);  // rows 0-1023: K-fold, 1024-2047: V^T
    _Float16* Wot   = (_Float16*)alloc(1024 * 1024 * 2);
    _Float16* W2t   = (_Float16*)alloc((size_t)4 * 1024 * 1024 * 2);  // per-batch folded kv@WO (^T)
    float*    bQf   = (float*)alloc(1024 * 4);
    float*    bkv   = (float*)alloc(2048 * 4);
    _Float16* U2    = (_Float16*)alloc(BIG);
    _Float16* KphiT = (_Float16*)alloc(BIG);
    _Float16* Vt    = (_Float16*)alloc(BIG);
    float*    kvpart= (float*)alloc((size_t)256 * 4096 * 4);
    float*    ksum  = (float*)alloc((size_t)64 * 64 * 4);

    // 1. precision converts
    cvt2_f16<<<16384, 256, 0, stream>>>(x, xb, y, yb, 16384 * 1024 / 8);
    cvt2_f16<<<1024, 256, 0, stream>>>(WQ, WQKb, WK, WQKb + (size_t)1024 * 1024, 1024 * 1024 / 8);
    // 2. omega block-diag + bias folds + ksum zero; weight transposes
    prep_all<<<4096, 256, 0, stream>>>(omega, bQ, bK, bV, obdT, bQf, bkv, ksum);
    transpose_cvt<<<dim3(16, 16), 256, 0, stream>>>(WV, Wkvt + (size_t)1024 * 1024);
    transpose_cvt<<<dim3(16, 16), 256, 0, stream>>>(WO, Wot);
    // 3. fold omega into WQ/WK
    gemm_fold<<<dim3(8, 16), 256, 0, stream>>>(WQKb, obdT, Wqt, Wkvt);
    // 4. K|V merged projection (K relu+eps transposed + fused ksum atomics; V linear transposed)
    gemm256<3><<<512, 512, 0, stream>>>(yb, Wkvt, bkv, KphiT, Vt, ksum, 16384, 2048, 1024, 8);
    // 5. kv partials, then fold kv into WO (per batch, scaled 1/4096)
    kvt_kernel<<<dim3(4, 64), 256, 0, stream>>>(Vt, KphiT, kvpart);
    w2t_kernel<<<dim3(8, 64), 256, 0, stream>>>(Wot, kvpart, W2t);
    // 6. Q projection with fused phi + divide -> U2 = qphi*4096/den
    gemm256<4><<<256, 512, 0, stream>>>(xb, Wqt, bQf, U2, ksum, nullptr, 16384, 1024, 1024, 4);
    // 7. output projection: out = U2 @ W2t(batch)^T + bO
    gemm256<2><<<256, 512, 0, stream>>>(U2, W2t, bO, d_out, nullptr, nullptr, 16384, 1024, 1024, 4);
}

// Round 9
// 261.349 us; speedup vs baseline: 1.1019x; 1.0721x over previous
//
#include <hip/hip_runtime.h>

#define EPSF 1e-6f

typedef _Float16 f16x8 __attribute__((ext_vector_type(8)));
typedef _Float16 f16x4 __attribute__((ext_vector_type(4)));
typedef float    f32x4 __attribute__((ext_vector_type(4)));

#define GLL16(gp, lp) __builtin_amdgcn_global_load_lds( \
    (const __attribute__((address_space(1))) void*)(gp), \
    (__attribute__((address_space(3))) void*)(lp), 16, 0, 0)

// ---------------- f32 -> f16 convert, two tensors in one dispatch ----------------
// grid MUST cover 2*n8each threads (one 8-elem item per thread)
__global__ __launch_bounds__(256) void cvt2_f16(const float* __restrict__ inA,
                                                _Float16* __restrict__ outA,
                                                const float* __restrict__ inB,
                                                _Float16* __restrict__ outB, int n8each) {
    int idx = blockIdx.x * 256 + threadIdx.x;
    const float* in = inA; _Float16* out = outA;
    if (idx >= n8each) { idx -= n8each; in = inB; out = outB; }
    const float4* p = (const float4*)in + (size_t)idx * 2;
    float4 a = p[0], b = p[1];
    f16x8 o;
    o[0] = (_Float16)a.x; o[1] = (_Float16)a.y; o[2] = (_Float16)a.z; o[3] = (_Float16)a.w;
    o[4] = (_Float16)b.x; o[5] = (_Float16)b.y; o[6] = (_Float16)b.z; o[7] = (_Float16)b.w;
    *(f16x8*)(out + (size_t)idx * 8) = o;
}

// ---------------- prep: block-diag omega^T (f16) + folded biases (interleaved) + ksum zero ----------------
__global__ __launch_bounds__(256) void prep_all(const float* __restrict__ omega,
                                                const float* __restrict__ bQ,
                                                const float* __restrict__ bK,
                                                const float* __restrict__ bV,
                                                _Float16* __restrict__ obdT,
                                                float* __restrict__ bQf,
                                                float* __restrict__ bkv,
                                                float* __restrict__ ksum) {
    int idx = blockIdx.x * 256 + threadIdx.x;   // over 1M
    int c = idx >> 10, k = idx & 1023;
    float v = ((c >> 6) == (k >> 6)) ? omega[(k & 63) * 64 + (c & 63)] : 0.f;
    obdT[idx] = (_Float16)v;
    if (idx < 4096) ksum[idx] = 0.f;            // zeroed every call (atomics target)
    if (idx < 1024) {
        int h = idx >> 6, e = idx & 63;
        float sq = 0.f, sk = 0.f;
        for (int d = 0; d < 64; d++) {
            float o = omega[d * 64 + e];
            sq += bQ[h * 64 + d] * o;
            sk += bK[h * 64 + d] * o;
        }
        bQf[idx] = sq;
        bkv[h * 128 + e] = sk;                  // interleaved per head: [K(64)|V(64)]
        bkv[h * 128 + 64 + e] = bV[idx];
    }
}

// ---------------- transpose 1024x1024 f32 -> f16 (vmode=1: V-interleave rows) ----------------
__global__ __launch_bounds__(256) void transpose_cvt(const float* __restrict__ in,
                                                     _Float16* __restrict__ out, int vmode) {
    __shared__ float tile[64][65];
    const int t = threadIdx.x;
    const int k0 = blockIdx.x * 64, n0 = blockIdx.y * 64;
#pragma unroll
    for (int j = 0; j < 16; j++) {
        int idx = j * 256 + t; int r = idx >> 6, c = idx & 63;
        tile[r][c] = in[(size_t)(k0 + r) * 1024 + n0 + c];
    }
    __syncthreads();
#pragma unroll
    for (int j = 0; j < 16; j++) {
        int idx = j * 256 + t; int rn = idx >> 6, ck = idx & 63;
        int rowo = n0 + rn;
        if (vmode) rowo = ((rowo >> 6) << 7) + 64 + (rowo & 63);
        out[(size_t)rowo * 1024 + k0 + ck] = (_Float16)tile[ck][rn];
    }
}

// ---------------- fold GEMM (m97 128^2): [WQ;WK](2048x1024) @ obdT^T ----------------
// out0 = Wqt (identity rows); out1 = Wkvt with K-interleave rows (h*128 + d)
__global__ __launch_bounds__(256) void gemm_fold(const _Float16* __restrict__ A,
                                                 const _Float16* __restrict__ Bt,
                                                 _Float16* __restrict__ out0,
                                                 _Float16* __restrict__ out1) {
    const int K = 1024;
    __shared__ __align__(16) _Float16 Asm[128 * 32];
    __shared__ __align__(16) _Float16 Bsm[128 * 32];
    const int t = threadIdx.x, lane = t & 63, w = t >> 6;
    const int bm = blockIdx.y * 128, bn = blockIdx.x * 128;
    const int wm = (w >> 1) * 64, wn = (w & 1) * 64;
    const int r15 = lane & 15, slog = lane >> 4;

    int aoff[4], boff[4];
#pragma unroll
    for (int m = 0; m < 4; m++) {
        int ra = wm + m * 16 + r15;
        aoff[m] = ra * 32 + (slog ^ ((ra >> 1) & 3)) * 8;
        int rb = wn + m * 16 + r15;
        boff[m] = rb * 32 + (slog ^ ((rb >> 1) & 3)) * 8;
    }
    f32x4 acc[4][4];
#pragma unroll
    for (int m = 0; m < 4; m++)
#pragma unroll
        for (int n = 0; n < 4; n++) acc[m][n] = (f32x4){0.f, 0.f, 0.f, 0.f};

    for (int kt = 0; kt < K; kt += 32) {
        __syncthreads();
#pragma unroll
        for (int i = 0; i < 2; i++) {
            int seg = i * 256 + w * 64 + lane;
            int r = seg >> 2, sp = seg & 3;
            int sg = sp ^ ((r >> 1) & 3);
            GLL16(A  + (size_t)(bm + r) * K + kt + sg * 8, Asm + (size_t)(i * 256 + w * 64) * 8);
            GLL16(Bt + (size_t)(bn + r) * K + kt + sg * 8, Bsm + (size_t)(i * 256 + w * 64) * 8);
        }
        __syncthreads();
        f16x8 av[4], bv[4];
#pragma unroll
        for (int m = 0; m < 4; m++) av[m] = *(const f16x8*)(Asm + aoff[m]);
#pragma unroll
        for (int n = 0; n < 4; n++) bv[n] = *(const f16x8*)(Bsm + boff[n]);
#pragma unroll
        for (int m = 0; m < 4; m++)
#pragma unroll
            for (int n = 0; n < 4; n++)
                acc[m][n] = __builtin_amdgcn_mfma_f32_16x16x32_f16(av[m], bv[n], acc[m][n], 0, 0, 0);
    }

#pragma unroll
    for (int m = 0; m < 4; m++) {
        int row0 = bm + wm + m * 16 + slog * 4;
        int l = row0 & 1023;
#pragma unroll
        for (int n = 0; n < 4; n++) {
            int colg = bn + wn + n * 16 + r15;
            f16x4 p;
#pragma unroll
            for (int j = 0; j < 4; j++) p[j] = (_Float16)acc[m][n][j];
            if (row0 < 1024) {
                *(f16x4*)(out0 + (size_t)colg * 1024 + l) = p;
            } else {
                int rr = ((colg >> 6) << 7) + (colg & 63);   // K-interleave
                *(f16x4*)(out1 + (size_t)rr * 1024 + l) = p;
            }
        }
    }
}

// ---------------- big GEMM: 256x256 tile, BK=32 slab, 4-slab ring, 16x16x32 MFMA ----------------
// (R3-verified core: counted vmcnt, 1 barrier/slab, rotate swizzle, 32 MFMA/slab/wave)
// EPI: 2 = linear -> f32 [M][N], Bt batched per 4096 rows
//      4 = relu+eps + fused divide by (qphi . ksum): U2 = qphi*4096/den -> f16 out0; out1 = ksum
//      5 = KV projection: phi(K) + fused kv mini-GEMM -> kvpart chunks (out0, layout [d][e]) + ksum atomics
template<int EPI>
__global__ __launch_bounds__(512, 2) void gemm256(const _Float16* __restrict__ A,
                                                  const _Float16* __restrict__ Bt,
                                                  const float* __restrict__ bias,
                                                  void* __restrict__ out0,
                                                  void* __restrict__ out1,
                                                  float* __restrict__ ksum,
                                                  int M, int N, int K, int nbn) {
    __shared__ __align__(16) char lds[131072];
    const int t = threadIdx.x, lane = t & 63, w = t >> 6;
    const int nwg = gridDim.x;
    const int f = (blockIdx.x & 7) * (nwg >> 3) + (blockIdx.x >> 3);   // bijective XCD swizzle
    const int bm = (f / nbn) * 256, bn = (f % nbn) * 256;
    const int wm = (w & 1) * 128, wn = (w >> 1) * 64;
    const int r15 = lane & 15, hi = lane >> 4;
    const int srow = lane >> 2, sp = lane & 3;     // staging: 16 rows/gll, 4 slots/row
    const _Float16* BtU = (EPI == 2) ? Bt + ((size_t)(bm >> 12) << 20) : Bt;  // per-batch B

    int aoff[8], boff[4];
#pragma unroll
    for (int m = 0; m < 8; m++) {
        int r = wm + m * 16 + r15;
        aoff[m] = r * 64 + (((hi + (r >> 1)) & 3) << 4);
    }
#pragma unroll
    for (int n = 0; n < 4; n++) {
        int r = wn + n * 16 + r15;
        boff[n] = r * 64 + (((hi + (r >> 1)) & 3) << 4);
    }

    f32x4 acc[8][4];
#pragma unroll
    for (int m = 0; m < 8; m++)
#pragma unroll
        for (int n = 0; n < 4; n++) acc[m][n] = (f32x4){0.f, 0.f, 0.f, 0.f};

    auto stage = [&](int s) {
        char* base = lds + (s & 3) * 32768;
        int kt = s * 32;
#pragma unroll
        for (int p = 0; p < 2; p++) {
            int row = w * 32 + p * 16 + srow;
            int sg = (sp - ((row >> 1) & 3)) & 3;   // pre-swizzled global slot
            GLL16(A   + (size_t)(bm + row) * K + kt + sg * 8, base + w * 2048 + p * 1024);
            GLL16(BtU + (size_t)(bn + row) * K + kt + sg * 8, base + 16384 + w * 2048 + p * 1024);
        }
    };

    const int NS = K >> 5;
    stage(0); stage(1); stage(2);
    for (int s = 0; s < NS; ++s) {
        if (s + 2 < NS)      asm volatile("s_waitcnt vmcnt(8)" ::: "memory");
        else if (s + 1 < NS) asm volatile("s_waitcnt vmcnt(4)" ::: "memory");
        else                 asm volatile("s_waitcnt vmcnt(0)" ::: "memory");
        asm volatile("s_barrier" ::: "memory");
        if (s + 3 < NS) stage(s + 3);               // slot (s-1)&3: reads done last slab
        const char* La = lds + (s & 3) * 32768;
        const char* Lb = La + 16384;
        f16x8 bv[4];
#pragma unroll
        for (int n = 0; n < 4; n++) bv[n] = *(const f16x8*)(Lb + boff[n]);
        f16x8 av[8];
#pragma unroll
        for (int m = 0; m < 8; m++) av[m] = *(const f16x8*)(La + aoff[m]);
        __builtin_amdgcn_s_setprio(1);
#pragma unroll
        for (int m = 0; m < 8; m++)
#pragma unroll
            for (int n = 0; n < 4; n++)
                acc[m][n] = __builtin_amdgcn_mfma_f32_16x16x32_f16(av[m], bv[n], acc[m][n], 0, 0, 0);
        __builtin_amdgcn_s_setprio(0);
    }

    if (EPI == 5) {
        // cols are head-interleaved [K_h|V_h]; quadrant q = w>>1: 0=K(g0) 1=V(g0) 2=K(g0+1) 3=V(g0+1)
        const int q = w >> 1;
        const bool isK = !(q & 1);
        const int nb = bm >> 12;
        const int g0 = bn >> 7;                 // first local head of this block's pair
        __syncthreads();                        // all slab reads done before LDS reuse
        char* LT = lds + q * 32768;             // tile [64 rows][512 B] (l-major within row)
        float cs[4] = {0.f, 0.f, 0.f, 0.f};
#pragma unroll
        for (int m = 0; m < 8; m++)
#pragma unroll
            for (int n = 0; n < 4; n++) {
                int dd = n * 16 + r15;
                float bs = bias[bn + wn + dd];
                f16x4 pk;
#pragma unroll
                for (int j = 0; j < 4; j++) {
                    float xv = acc[m][n][j] + bs;
                    if (isK) { xv = fmaxf(xv, 0.f) + EPSF; cs[n] += xv; }
                    pk[j] = (_Float16)xv;
                }
                int l2 = (wm + m * 16 + hi * 4) * 2;
                *(f16x4*)(LT + dd * 512 + (l2 ^ ((dd & 7) << 4))) = pk;
            }
        if (isK) {   // fused ksum: this wave covers 128 l-rows of head g0+(q>>1)
#pragma unroll
            for (int n = 0; n < 4; n++) {
                cs[n] += __shfl_xor(cs[n], 16, 64);
                cs[n] += __shfl_xor(cs[n], 32, 64);
            }
            if (hi == 0) {
#pragma unroll
                for (int n = 0; n < 4; n++)
                    atomicAdd(ksum + (size_t)(nb * 16 + g0 + (q >> 1)) * 64 + n * 16 + r15, cs[n]);
            }
        }
        __syncthreads();
        // mini-GEMM kv[d][e] = sum_l Kphi[l][d]*V[l][e] over this block's 256 rows.
        // 32 output 16x16 tiles (2 heads x 4x4); wave w owns tiles w*4 .. w*4+3.
        f32x4 kva[4];
#pragma unroll
        for (int i = 0; i < 4; i++) kva[i] = (f32x4){0.f, 0.f, 0.f, 0.f};
#pragma unroll
        for (int i = 0; i < 4; i++) {
            int tt = w * 4 + i;
            int hl = tt >> 4, dg = (tt >> 2) & 3, eg = tt & 3;
            const char* KT = lds + (hl * 2) * 32768;
            const char* VT = lds + (hl * 2 + 1) * 32768;
            int d = dg * 16 + r15, e = eg * 16 + r15;
#pragma unroll
            for (int ks = 0; ks < 8; ks++) {
                int l2 = (ks * 32 + hi * 8) * 2;
                f16x8 ka = *(const f16x8*)(KT + d * 512 + (l2 ^ ((d & 7) << 4)));
                f16x8 vb = *(const f16x8*)(VT + e * 512 + (l2 ^ ((e & 7) << 4)));
                kva[i] = __builtin_amdgcn_mfma_f32_16x16x32_f16(ka, vb, kva[i], 0, 0, 0);
            }
        }
        const int chunk = (bm >> 8) & 15;
        float* kvp = (float*)out0;
#pragma unroll
        for (int i = 0; i < 4; i++) {
            int tt = w * 4 + i;
            int hl = tt >> 4, dg = (tt >> 2) & 3, eg = tt & 3;
            float* dst = kvp + ((size_t)(nb * 16 + g0 + hl) * 16 + chunk) * 4096;
#pragma unroll
            for (int j = 0; j < 4; j++)
                dst[(dg * 16 + hi * 4 + j) * 64 + eg * 16 + r15] = kva[i][j];
        }
    } else if (EPI == 4) {
        // relu+eps, then divide by den = qphi . ksum[head] (wave owns one head's 64 cols)
        const int headg = (bm >> 12) * 16 + ((bn + wn) >> 6);
        const float* ks = (const float*)out1;
        float ksn[4];
#pragma unroll
        for (int n = 0; n < 4; n++) ksn[n] = ks[(size_t)headg * 64 + n * 16 + r15];
        _Float16* C = (_Float16*)out0;
#pragma unroll
        for (int m = 0; m < 8; m++) {
            int row0 = bm + wm + m * 16 + hi * 4;
            float qv[4][4], dp[4] = {0.f, 0.f, 0.f, 0.f};
#pragma unroll
            for (int n = 0; n < 4; n++) {
                int colg = bn + wn + n * 16 + r15;
                float bs = bias[colg];
#pragma unroll
                for (int j = 0; j < 4; j++) {
                    float xv = fmaxf(acc[m][n][j] + bs, 0.f) + EPSF;
                    qv[n][j] = xv;
                    dp[j] += xv * ksn[n];
                }
            }
#pragma unroll
            for (int j = 0; j < 4; j++) {       // reduce over the 16 r15 lanes
                dp[j] += __shfl_xor(dp[j], 1, 64);
                dp[j] += __shfl_xor(dp[j], 2, 64);
                dp[j] += __shfl_xor(dp[j], 4, 64);
                dp[j] += __shfl_xor(dp[j], 8, 64);
                dp[j] = 4096.0f * __builtin_amdgcn_rcpf(dp[j]);
            }
#pragma unroll
            for (int n = 0; n < 4; n++) {
                int colg = bn + wn + n * 16 + r15;
#pragma unroll
                for (int j = 0; j < 4; j++)
                    C[(size_t)(row0 + j) * N + colg] = (_Float16)(qv[n][j] * dp[j]);
            }
        }
    } else {
#pragma unroll
        for (int m = 0; m < 8; m++) {
            int row0 = bm + wm + m * 16 + hi * 4;
#pragma unroll
            for (int n = 0; n < 4; n++) {
                int colg = bn + wn + n * 16 + r15;
                float bs = bias ? bias[colg] : 0.f;
#pragma unroll
                for (int j = 0; j < 4; j++)
                    ((float*)out0)[(size_t)(row0 + j) * N + colg] = acc[m][n][j] + bs;
            }
        }
    }
}

// ---------------- reduce 16 chunks -> kvT[head][d][e] ----------------
__global__ __launch_bounds__(256) void kvred16(const float* __restrict__ kvpart,
                                               float* __restrict__ kvT) {
    int gh = blockIdx.x, t = threadIdx.x;
    const float* kp = kvpart + (size_t)gh * 16 * 4096;
#pragma unroll
    for (int i = 0; i < 16; i++) {
        int idx = i * 256 + t;
        float s = 0.f;
#pragma unroll
        for (int c = 0; c < 16; c++) s += kp[c * 4096 + idx];
        kvT[(size_t)gh * 4096 + idx] = s;
    }
}

// ---------------- W2t[b][j][hl*64+d] = (1/4096) sum_e Wot[j][hl*64+e] * kv[gh][d][e] ----------------
// kvT layout is [d][e] (d*64+e); store TRANSPOSED into kvL so kvL[e][d] = kv[d][e].
__global__ __launch_bounds__(256) void w2t_kernel(const _Float16* __restrict__ Wot,
                                                  const float* __restrict__ kvT,
                                                  _Float16* __restrict__ W2t) {
    const int t = threadIdx.x;
    const int jb = blockIdx.x;      // 0..7 (128 j-rows each)
    const int gh = blockIdx.y;      // 0..63 global head
    const int b = gh >> 4, hl = gh & 15;
    __shared__ float kvL[64][65];
    const float* kp = kvT + (size_t)gh * 4096;
#pragma unroll
    for (int i = 0; i < 16; i++) {
        int idx = i * 256 + t;
        kvL[idx & 63][idx >> 6] = kp[idx];   // kvL[e][d] = kv[d][e]
    }
    __syncthreads();
    const int j = jb * 128 + (t >> 1);
    const int d0 = (t & 1) * 32;
    const _Float16* wr = Wot + (size_t)j * 1024 + hl * 64;
    float wv[64];
#pragma unroll
    for (int i = 0; i < 8; i++) {
        f16x8 v = *(const f16x8*)(wr + i * 8);
#pragma unroll
        for (int k = 0; k < 8; k++) wv[i * 8 + k] = (float)v[k];
    }
    _Float16* outp = W2t + ((size_t)b << 20) + (size_t)j * 1024 + hl * 64 + d0;
#pragma unroll
    for (int d = 0; d < 32; d++) {
        float s = 0.f;
#pragma unroll
        for (int e = 0; e < 64; e++) s += wv[e] * kvL[e][d0 + d];
        outp[d] = (_Float16)(s * (1.0f / 4096.0f));
    }
}

// ------------------------------------------------------------------------------------
extern "C" void kernel_launch(void* const* d_in, const int* in_sizes, int n_in,
                              void* d_out, int out_size, void* d_ws, size_t ws_size,
                              hipStream_t stream) {
    (void)in_sizes; (void)n_in; (void)out_size; (void)ws_size;
    const float* x     = (const float*)d_in[0];
    const float* y     = (const float*)d_in[1];
    const float* WQ    = (const float*)d_in[2];
    const float* bQ    = (const float*)d_in[3];
    const float* WK    = (const float*)d_in[4];
    const float* bK    = (const float*)d_in[5];
    const float* WV    = (const float*)d_in[6];
    const float* bV    = (const float*)d_in[7];
    const float* WO    = (const float*)d_in[8];
    const float* bO    = (const float*)d_in[9];
    const float* omega = (const float*)d_in[10];

    char* ws = (char*)d_ws;
    size_t off = 0;
    auto alloc = [&](size_t bytes) { void* p = ws + off; off += (bytes + 255) & ~(size_t)255; return p; };
    const size_t BIG = (size_t)16384 * 1024 * 2;    // 32 MiB f16
    _Float16* xb    = (_Float16*)alloc(BIG);
    _Float16* yb    = (_Float16*)alloc(BIG);
    _Float16* WQKb  = (_Float16*)alloc((size_t)2048 * 1024 * 2);  // stacked WQ;WK f16
    _Float16* obdT  = (_Float16*)alloc(1024 * 1024 * 2);
    _Float16* Wqt   = (_Float16*)alloc(1024 * 1024 * 2);
    _Float16* Wkvt  = (_Float16*)alloc((size_t)2048 * 1024 * 2);  // interleaved rows h*128+[K|V]
    _Float16* Wot   = (_Float16*)alloc(1024 * 1024 * 2);
    _Float16* W2t   = (_Float16*)alloc((size_t)4 * 1024 * 1024 * 2);  // per-batch folded kv@WO (^T)
    float*    bQf   = (float*)alloc(1024 * 4);
    float*    bkv   = (float*)alloc(2048 * 4);
    _Float16* U2    = (_Float16*)alloc(BIG);
    float*    kvpart= (float*)alloc((size_t)64 * 16 * 4096 * 4);  // [head][chunk][64][64] (d,e)
    float*    kvT   = (float*)alloc((size_t)64 * 4096 * 4);
    float*    ksum  = (float*)alloc((size_t)64 * 64 * 4);

    // 1. precision converts
    cvt2_f16<<<16384, 256, 0, stream>>>(x, xb, y, yb, 16384 * 1024 / 8);
    cvt2_f16<<<1024, 256, 0, stream>>>(WQ, WQKb, WK, WQKb + (size_t)1024 * 1024, 1024 * 1024 / 8);
    // 2. omega block-diag + interleaved bias folds + ksum zero; weight transposes
    prep_all<<<4096, 256, 0, stream>>>(omega, bQ, bK, bV, obdT, bQf, bkv, ksum);
    transpose_cvt<<<dim3(16, 16), 256, 0, stream>>>(WV, Wkvt, 1);   // V-interleave rows
    transpose_cvt<<<dim3(16, 16), 256, 0, stream>>>(WO, Wot, 0);
    // 3. fold omega into WQ/WK (out1 = K-interleaved rows of Wkvt)
    gemm_fold<<<dim3(8, 16), 256, 0, stream>>>(WQKb, obdT, Wqt, Wkvt);
    // 4. K|V projection with fused phi + in-epilogue kv mini-GEMM + ksum atomics
    //    (KphiT/Vt never materialized)
    gemm256<5><<<512, 512, 0, stream>>>(yb, Wkvt, bkv, kvpart, nullptr, ksum, 16384, 2048, 1024, 8);
    // 5. reduce kv chunks; fold kv into WO (per batch, scaled 1/4096)
    kvred16<<<64, 256, 0, stream>>>(kvpart, kvT);
    w2t_kernel<<<dim3(8, 64), 256, 0, stream>>>(Wot, kvT, W2t);
    // 6. Q projection with fused phi + divide -> U2 = qphi*4096/den
    gemm256<4><<<256, 512, 0, stream>>>(xb, Wqt, bQf, U2, ksum, nullptr, 16384, 1024, 1024, 4);
    // 7. output projection: out = U2 @ W2t(batch)^T + bO
    gemm256<2><<<256, 512, 0, stream>>>(U2, W2t, bO, d_out, nullptr, nullptr, 16384, 1024, 1024, 4);
}